// Round 8
// baseline (1554.878 us; speedup 1.0000x reference)
//
#include <hip/hip_runtime.h>
#include <hip/hip_bf16.h>

#define DM 512
#define NH 8
#define DK 64
#define SEQ 512
#define NB 8
#define NL 6
#define DFF 2048
#define OUTD 1000
#define EMB_SCALE 22.627416997969522f
#define PE_C (-0.017988946039015984f)   // -ln(10000)/512

typedef __bf16 bf16x8 __attribute__((ext_vector_type(8)));
typedef __bf16 bf16x4 __attribute__((ext_vector_type(4)));
typedef float f32x4 __attribute__((ext_vector_type(4)));

__device__ __forceinline__ void load16_lds(const __bf16* g, __bf16* l) {
  __builtin_amdgcn_global_load_lds(
      (const __attribute__((address_space(1))) void*)g,
      (__attribute__((address_space(3))) void*)l, 16, 0, 0);
}

__device__ __forceinline__ float dot8(bf16x8 w, const float* a) {
  float s = 0.f;
#pragma unroll
  for (int j = 0; j < 8; ++j) s += (float)w[j] * a[j];
  return s;
}

// block-wide LN over a 512-elem row held as (v0 @ tid, v1 @ tid+256).
__device__ __forceinline__ void ln_pair(float v0, float v1, int tid,
                                        const float* __restrict__ g,
                                        const float* __restrict__ beta,
                                        float* out, float* ps, float* pq) {
  float s = v0 + v1, sq = v0 * v0 + v1 * v1;
  for (int o = 32; o > 0; o >>= 1) { s += __shfl_xor(s, o); sq += __shfl_xor(sq, o); }
  int wv = tid >> 6;
  if ((tid & 63) == 0) { ps[wv] = s; pq[wv] = sq; }
  __syncthreads();
  s = ps[0] + ps[1] + ps[2] + ps[3];
  sq = pq[0] + pq[1] + pq[2] + pq[3];
  float mean = s * (1.f / DM);
  float rstd = rsqrtf(sq * (1.f / DM) - mean * mean + 1e-5f);
  out[tid] = (v0 - mean) * rstd * g[tid] + beta[tid];
  out[tid + 256] = (v1 - mean) * rstd * g[tid + 256] + beta[tid + 256];
  __syncthreads();
}

// ---------------- PE table ----------------
__global__ __launch_bounds__(256) void pe_kernel(float* __restrict__ pe) {
  int s = blockIdx.x;
  int d2 = threadIdx.x;
  float div = expf((float)(2 * d2) * PE_C);
  float arg = (float)s * div;
  pe[(size_t)s * DM + 2 * d2] = sinf(arg);
  pe[(size_t)s * DM + 2 * d2 + 1] = cosf(arg);
}

// ---------------- embedding (float2 vectorized) ----------------
__global__ __launch_bounds__(256) void embed_enc(const int* __restrict__ x,
                                                 const float* __restrict__ emb,
                                                 const float* __restrict__ pe,
                                                 float* __restrict__ e,
                                                 __bf16* __restrict__ eb) {
  int idx = blockIdx.x * 256 + threadIdx.x;   // 2-elem granule index
  int d2 = idx & 255;
  int bs = idx >> 8;
  int s = bs & (SEQ - 1);
  int tok = x[bs];
  float2 ev = ((const float2*)(emb + (size_t)tok * DM))[d2];
  float2 pv = ((const float2*)(pe + (size_t)s * DM))[d2];
  float v0 = ev.x * EMB_SCALE + pv.x;
  float v1 = ev.y * EMB_SCALE + pv.y;
  ((float2*)e)[idx] = make_float2(v0, v1);
  union { __bf16 h[2]; unsigned u; } pk;
  pk.h[0] = (__bf16)v0; pk.h[1] = (__bf16)v1;
  ((unsigned*)eb)[idx] = pk.u;
}

// ---------------- merged weight transpose fp32[K][N] -> bf16[N][K] ---------
__global__ __launch_bounds__(256) void transpose_w3(
    const float* __restrict__ W0, __bf16* __restrict__ T0, int n0,
    const float* __restrict__ W1, __bf16* __restrict__ T1, int n1,
    const float* __restrict__ W2, __bf16* __restrict__ T2,
    long zmul2, long zadd2, int K, int N) {
  __shared__ float t[32][33];
  int z = blockIdx.z;
  const float* W;
  __bf16* WT;
  if (z < n0) {
    W = W0 + (size_t)z * K * N; WT = T0 + (size_t)z * K * N;
  } else if (z < n0 + n1) {
    int zz = z - n0;
    W = W1 + (size_t)zz * K * N; WT = T1 + (size_t)zz * K * N;
  } else {
    int zz = z - n0 - n1;
    W = W2 + (size_t)(zz * zmul2 + zadd2) * K * N;
    WT = T2 + (size_t)zz * K * N;
  }
  int k0 = blockIdx.y * 32, n0b = blockIdx.x * 32;
  int tx = threadIdx.x & 7, ty = threadIdx.x >> 3;
  float4 v = *(const float4*)&W[(size_t)(k0 + ty) * N + n0b + tx * 4];
  t[ty][tx * 4 + 0] = v.x; t[ty][tx * 4 + 1] = v.y;
  t[ty][tx * 4 + 2] = v.z; t[ty][tx * 4 + 3] = v.w;
  __syncthreads();
  bf16x4 o;
  o[0] = (__bf16)t[tx * 4 + 0][ty];
  o[1] = (__bf16)t[tx * 4 + 1][ty];
  o[2] = (__bf16)t[tx * 4 + 2][ty];
  o[3] = (__bf16)t[tx * 4 + 3][ty];
  *(bf16x4*)&WT[(size_t)(n0b + ty) * K + k0 + tx * 4] = o;
}

// out_w fp32 [512][1000] -> bf16 [1000][512] (guarded tail)
__global__ __launch_bounds__(256) void transpose_ow(const float* __restrict__ W,
                                                    __bf16* __restrict__ WT) {
  __shared__ float t[32][33];
  int n0 = blockIdx.x * 32, k0 = blockIdx.y * 32;
  int tid = threadIdx.x;
  for (int i = tid; i < 1024; i += 256) {
    int kk = i >> 5, nn = i & 31;
    t[kk][nn] = (n0 + nn < OUTD) ? W[(size_t)(k0 + kk) * OUTD + n0 + nn] : 0.f;
  }
  __syncthreads();
  for (int i = tid; i < 1024; i += 256) {
    int nn = i >> 5, kk = i & 31;
    if (n0 + nn < OUTD)
      WT[(size_t)(n0 + nn) * DM + k0 + kk] = (__bf16)t[kk][nn];
  }
}

// ---------------- MFMA GEMM: stage-B-once + A-direct -----------------------
// A elements have 1x in-block LDS reuse and B only 2x, so staging both costs
// 16 vmcnt(0)+barrier drains per block for almost no reuse (m169/m233 lesson).
// New structure: B panel (64 x 512, 64KB, XOR-swizzled) staged ONCE -> one
// barrier per 512-K chunk; A fragments read directly from global (L1/L2).
// K-loop is barrier-free; ILP hides L2 latency.
template <int BN, int SK, bool RELU, bool WF32, bool WBF16, bool TRV, bool KVM>
__global__ __launch_bounds__(256) void mfma_gemm(
    const __bf16* __restrict__ A, const __bf16* __restrict__ BT,
    const float* __restrict__ bias, float* __restrict__ C,
    __bf16* __restrict__ Cb, __bf16* __restrict__ Vt, int M, int N, int K,
    long btStride, long bStride, long cStride) {
  static_assert(BN == 64, "structure assumes BN=64");
  // XCD swizzle: each XCD owns a contiguous y-chunk; x fastest, z slowest.
  int gx = gridDim.x, gy = gridDim.y;
  int lin = blockIdx.x + gx * (blockIdx.y + gy * blockIdx.z);
  int xcd = lin & 7, li = lin >> 3;
  int yc = gy >> 3;
  int bx = li % gx;
  int t2 = li / gx;
  int by = xcd * yc + (t2 % yc);
  int z = t2 / yc;

  if (SK == 1) {
    if (KVM) {
      long idx = (long)(z >> 1) * 3 + 1 + (z & 1);
      BT += idx * btStride;
      bias += idx * bStride;
    } else {
      BT += (size_t)z * btStride;
      bias += (size_t)z * bStride;
    }
  }
  if (WF32) C += (size_t)z * cStride;
  if (WBF16) Cb += (size_t)z * cStride;

  __shared__ __bf16 Bs[64 * 512];      // Bs[row][c] = B[n0+row][c ^ (row&7)] (16B chunks)

  int tid = threadIdx.x;
  int wave = tid >> 6, lane = tid & 63;
  int wm = wave >> 1, wn = wave & 1;   // 2 x 2 wave grid
  int quad = lane >> 4, l16 = lane & 15;
  int m0 = by * 128, n0 = bx * BN;

  f32x4 acc[4][2];
#pragma unroll
  for (int i = 0; i < 4; ++i)
#pragma unroll
    for (int j = 0; j < 2; ++j) acc[i][j] = (f32x4){0.f, 0.f, 0.f, 0.f};

  int kLen = (SK > 1) ? (K / SK) : K;
  int kBeg = (SK > 1) ? z * kLen : 0;
  const int NC = kLen >> 9;            // 512-wide chunks

  // per-wave A row bases (4 rows of fragments, fixed all kernel)
  const __bf16* arow[4];
#pragma unroll
  for (int i = 0; i < 4; ++i)
    arow[i] = A + (size_t)(m0 + wm * 64 + i * 16 + l16) * K + kBeg;

  for (int c = 0; c < NC; ++c) {
    if (c) __syncthreads();            // all reads of Bs done before overwrite
    int kc = kBeg + (c << 9);
    // stage B panel: 16 rounds, one 1024B row per wave per round.
    // source col pre-swizzled so linear LDS write lands XOR-swizzled (m173).
#pragma unroll
    for (int j = 0; j < 16; ++j) {
      int row = j * 4 + wave;
      load16_lds(&BT[(size_t)(n0 + row) * K + kc + ((lane ^ (row & 7)) << 3)],
                 &Bs[row * 512]);
    }
    __syncthreads();                   // vmcnt(0) drain: panel ready
    int cof = c << 9;
#pragma unroll 2
    for (int kt = 0; kt < 8; ++kt) {
#pragma unroll
      for (int kk = 0; kk < 64; kk += 32) {
        bf16x8 af[4], bfr[2];
#pragma unroll
        for (int i = 0; i < 4; ++i)
          af[i] = *(const bf16x8*)&arow[i][cof + kt * 64 + kk + quad * 8];
#pragma unroll
        for (int i = 0; i < 2; ++i) {
          int row = wn * 32 + i * 16 + l16;
          int ck = kt * 8 + (kk >> 3) + quad;
          bfr[i] = *(const bf16x8*)&Bs[row * 512 + ((ck ^ (row & 7)) << 3)];
        }
#pragma unroll
        for (int mi = 0; mi < 4; ++mi)
#pragma unroll
          for (int ni = 0; ni < 2; ++ni)
            acc[mi][ni] = __builtin_amdgcn_mfma_f32_16x16x32_bf16(
                af[mi], bfr[ni], acc[mi][ni], 0, 0, 0);
      }
    }
  }

#pragma unroll
  for (int ni = 0; ni < 2; ++ni) {
    int col = n0 + wn * 32 + ni * 16 + l16;
    float bv = (SK == 1 || z == 0) ? bias[col] : 0.f;
    if (TRV && z == 2) {
      int b = m0 >> 9;
#pragma unroll
      for (int mi = 0; mi < 4; ++mi) {
        int srow = (m0 & 511) + wm * 64 + mi * 16 + quad * 4;
        bf16x4 pk;
#pragma unroll
        for (int r = 0; r < 4; ++r) pk[r] = (__bf16)(acc[mi][ni][r] + bv);
        *(bf16x4*)&Vt[((size_t)(b * 512 + col)) * 512 + srow] = pk;
      }
    } else {
#pragma unroll
      for (int mi = 0; mi < 4; ++mi) {
#pragma unroll
        for (int r = 0; r < 4; ++r) {
          int row = m0 + wm * 64 + mi * 16 + quad * 4 + r;
          float v = acc[mi][ni][r] + bv;
          if (RELU) v = fmaxf(v, 0.f);
          if (WF32) C[(size_t)row * N + col] = v;
          if (WBF16) Cb[(size_t)row * N + col] = (__bf16)v;
        }
      }
    }
  }
}

// ---------------- MFMA encoder attention: zero K/V staging -----------------
// K/V panels per (b,h) are 64KB and L2-resident across the 32 blocks sharing
// them (m169: staging L2-fitting data is pure overhead). Fragments read
// directly from global; only 2 barriers per block (around softmax).
#define SCP 520
__global__ __launch_bounds__(256) void attn_mfma(const __bf16* __restrict__ QKV,
                                                 const __bf16* __restrict__ Vt,
                                                 float* __restrict__ O) {
  __shared__ __bf16 Sc[16 * SCP];

  const long ACTL = (long)NB * SEQ * DM;
  int tid = threadIdx.x;
  int wave = tid >> 6, lane = tid & 63;
  int quad = lane >> 4, l16 = lane & 15;
  // XCD swizzle: chunk by bh so each XCD's L2 holds few K/V panels.
  int lin = blockIdx.x + gridDim.x * blockIdx.y;
  int xcd = lin & 7, li = lin >> 3;
  int yc = gridDim.y >> 3;
  int q0 = (li % gridDim.x) * 16;
  int bh = xcd * yc + li / gridDim.x;
  int b = bh >> 3, h = bh & 7;
  const __bf16* Q = QKV;
  const __bf16* Kp = QKV + ACTL;
  size_t baseQ = ((size_t)b * SEQ + q0) * DM + h * DK;
  size_t baseK = ((size_t)b * SEQ) * DM + h * DK;
  const __bf16* VtB = Vt + ((size_t)(b * 512 + h * 64)) * 512;

  bf16x8 af0 = *(const bf16x8*)&Q[baseQ + (size_t)l16 * DM + quad * 8];
  bf16x8 af1 = *(const bf16x8*)&Q[baseQ + (size_t)l16 * DM + 32 + quad * 8];

  // ---- QK^T, 8 tiles, direct K reads, no barriers ----
  int krow = wave * 16 + l16;
#pragma unroll 2
  for (int kt = 0; kt < 8; ++kt) {
    const __bf16* kp = &Kp[baseK + (size_t)(kt * 64 + krow) * DM];
    bf16x8 b0 = *(const bf16x8*)&kp[quad * 8];
    bf16x8 b1 = *(const bf16x8*)&kp[32 + quad * 8];
    f32x4 acc = (f32x4){0.f, 0.f, 0.f, 0.f};
    acc = __builtin_amdgcn_mfma_f32_16x16x32_bf16(af0, b0, acc, 0, 0, 0);
    acc = __builtin_amdgcn_mfma_f32_16x16x32_bf16(af1, b1, acc, 0, 0, 0);
#pragma unroll
    for (int r = 0; r < 4; ++r)
      Sc[(quad * 4 + r) * SCP + kt * 64 + wave * 16 + l16] =
          (__bf16)(acc[r] * 0.125f);
  }
  __syncthreads();

  // ---- softmax over 16 rows ----
#pragma unroll
  for (int rr = 0; rr < 4; ++rr) {
    int r = wave * 4 + rr;
    float v[8];
    float mx = -1e30f;
#pragma unroll
    for (int j = 0; j < 8; ++j) {
      v[j] = (float)Sc[r * SCP + j * 64 + lane];
      mx = fmaxf(mx, v[j]);
    }
    for (int o = 32; o > 0; o >>= 1) mx = fmaxf(mx, __shfl_xor(mx, o));
    float sum = 0.f;
#pragma unroll
    for (int j = 0; j < 8; ++j) { v[j] = __expf(v[j] - mx); sum += v[j]; }
    for (int o = 32; o > 0; o >>= 1) sum += __shfl_xor(sum, o);
    float inv = 1.f / sum;
#pragma unroll
    for (int j = 0; j < 8; ++j)
      Sc[r * SCP + j * 64 + lane] = (__bf16)(v[j] * inv);
  }
  __syncthreads();

  // ---- PV, 8 tiles, direct V^T reads, no barriers ----
  f32x4 oacc = (f32x4){0.f, 0.f, 0.f, 0.f};
  int drow = wave * 16 + l16;
#pragma unroll 2
  for (int kt = 0; kt < 8; ++kt) {
#pragma unroll
    for (int kk = 0; kk < 64; kk += 32) {
      bf16x8 pa = *(const bf16x8*)&Sc[l16 * SCP + kt * 64 + kk + quad * 8];
      bf16x8 vb = *(const bf16x8*)&VtB[(size_t)drow * 512 + kt * 64 + kk + quad * 8];
      oacc = __builtin_amdgcn_mfma_f32_16x16x32_bf16(pa, vb, oacc, 0, 0, 0);
    }
  }
#pragma unroll
  for (int r = 0; r < 4; ++r)
    O[((size_t)b * SEQ + q0 + quad * 4 + r) * DM + h * DK + wave * 16 + l16] =
        oacc[r];
}

// ---------------- residual + layernorm (float2 vectorized) -------
template <bool WB>
__global__ __launch_bounds__(256) void add_ln(
    const float* __restrict__ x, const float* __restrict__ x2,
    const float* __restrict__ res, const float* __restrict__ cbias,
    const float* __restrict__ g, const float* __restrict__ beta,
    float* __restrict__ y, __bf16* __restrict__ yb) {
  int row = blockIdx.x;
  int tid = threadIdx.x;                // one float2 (cols 2t,2t+1) per thread
  float2 xv = ((const float2*)(x + (size_t)row * DM))[tid];
  float2 rv = ((const float2*)(res + (size_t)row * DM))[tid];
  float v0 = xv.x + rv.x;
  float v1 = xv.y + rv.y;
  if (cbias) {
    float2 cb = ((const float2*)cbias)[tid];
    v0 += cb.x; v1 += cb.y;
  }
  if (x2) {
    float2 x2v = ((const float2*)(x2 + (size_t)row * DM))[tid];
    v0 += x2v.x; v1 += x2v.y;
  }
  float s = v0 + v1, sq = v0 * v0 + v1 * v1;
  for (int o = 32; o > 0; o >>= 1) {
    s += __shfl_xor(s, o);
    sq += __shfl_xor(sq, o);
  }
  __shared__ float ps[4], pq[4];
  int wv = tid >> 6;
  if ((tid & 63) == 0) { ps[wv] = s; pq[wv] = sq; }
  __syncthreads();
  s = ps[0] + ps[1] + ps[2] + ps[3];
  sq = pq[0] + pq[1] + pq[2] + pq[3];
  float mean = s * (1.f / DM);
  float var = sq * (1.f / DM) - mean * mean;
  float rstd = rsqrtf(var + 1e-5f);
  float2 gg = ((const float2*)g)[tid];
  float2 bb = ((const float2*)beta)[tid];
  float o0 = (v0 - mean) * rstd * gg.x + bb.x;
  float o1 = (v1 - mean) * rstd * gg.y + bb.y;
  ((float2*)(y + (size_t)row * DM))[tid] = make_float2(o0, o1);
  if (WB) {
    union { __bf16 h[2]; unsigned u; } pk;
    pk.h[0] = (__bf16)o0; pk.h[1] = (__bf16)o1;
    ((unsigned*)(yb + (size_t)row * DM))[tid] = pk.u;
  }
}

// ============ fused decoder (3 dispatches/layer) ============

// one block per (b,h); LN1/LN3 recomputed redundantly per block (cheap)
template <bool FIRST>
__global__ __launch_bounds__(256) void dec_attn(
    const float* __restrict__ dfp, const float* __restrict__ xp,
    const float* __restrict__ g3, const float* __restrict__ b3,
    const int* __restrict__ target, const float* __restrict__ emb,
    const __bf16* __restrict__ WvT, const float* __restrict__ bv,
    const float* __restrict__ g1, const float* __restrict__ b1ln,
    const __bf16* __restrict__ WqT, const float* __restrict__ qb,
    const __bf16* __restrict__ Kb, const __bf16* __restrict__ Vb,
    float* __restrict__ da, float* __restrict__ tbuf) {
  __shared__ float arow[DM];
  __shared__ float trow[DM];
  __shared__ float red[4][64];
  __shared__ float q[64];
  __shared__ float sc[SEQ];
  __shared__ float wred[4];
  __shared__ float ps[4], pq[4];

  int bh = blockIdx.x, b = bh >> 3, h = bh & 7;
  int tid = threadIdx.x, lane = tid & 63, wave = tid >> 6;

  // ---- dd (layer input) ----
  if (FIRST) {
    int tok = target[b];
    arow[tid] = emb[(size_t)tok * DM + tid] * EMB_SCALE + ((tid & 1) ? 1.f : 0.f);
    arow[tid + 256] =
        emb[(size_t)tok * DM + tid + 256] * EMB_SCALE + ((tid & 1) ? 1.f : 0.f);
    __syncthreads();
  } else {
    float v0 = dfp[(size_t)b * DM + tid] + xp[(size_t)b * DM + tid];
    float v1 = dfp[(size_t)b * DM + tid + 256] + xp[(size_t)b * DM + tid + 256];
    ln_pair(v0, v1, tid, g3, b3, arow, ps, pq);
  }

  // ---- t = LN1(dd + dd@Wv + bv) ----
  float o0, o1;
  {
    const __bf16* w = &WvT[(size_t)tid * DM];
    float acc = 0.f;
#pragma unroll 4
    for (int k = 0; k < DM; k += 8) acc += dot8(*(const bf16x8*)&w[k], &arow[k]);
    o0 = arow[tid] + acc + bv[tid];
  }
  {
    const __bf16* w = &WvT[(size_t)(tid + 256) * DM];
    float acc = 0.f;
#pragma unroll 4
    for (int k = 0; k < DM; k += 8) acc += dot8(*(const bf16x8*)&w[k], &arow[k]);
    o1 = arow[tid + 256] + acc + bv[tid + 256];
  }
  ln_pair(o0, o1, tid, g1, b1ln, trow, ps, pq);
  if (h == 0) {
    tbuf[(size_t)b * DM + tid] = trow[tid];
    tbuf[(size_t)b * DM + tid + 256] = trow[tid + 256];
  }

  // ---- q-gemv: 64 cols x 4 k-subs from trow ----
  {
    int c = tid & 63, s = tid >> 6;
    const __bf16* w = &WqT[(size_t)(h * 64 + c) * DM + s * 128];
    float acc = 0.f;
#pragma unroll
    for (int k = 0; k < 128; k += 8)
      acc += dot8(*(const bf16x8*)&w[k], &trow[s * 128 + k]);
    red[s][c] = acc;
  }
  __syncthreads();
  if (tid < 64)
    q[tid] = red[0][tid] + red[1][tid] + red[2][tid] + red[3][tid] + qb[h * 64 + tid];
  __syncthreads();

  // ---- scores ----
  for (int key = tid; key < SEQ; key += 256) {
    const __bf16* kp = &Kb[((size_t)b * SEQ + key) * DM + h * 64];
    float acc = 0.f;
#pragma unroll
    for (int k = 0; k < 64; k += 8) acc += dot8(*(const bf16x8*)&kp[k], &q[k]);
    sc[key] = acc * 0.125f;
  }
  __syncthreads();
  float m = -1e30f;
  for (int j = tid; j < SEQ; j += 256) m = fmaxf(m, sc[j]);
  for (int o = 32; o > 0; o >>= 1) m = fmaxf(m, __shfl_xor(m, o));
  if (lane == 0) wred[wave] = m;
  __syncthreads();
  m = fmaxf(fmaxf(wred[0], wred[1]), fmaxf(wred[2], wred[3]));
  float sum = 0.f;
  for (int j = tid; j < SEQ; j += 256) {
    float p = __expf(sc[j] - m);
    sc[j] = p;
    sum += p;
  }
  for (int o = 32; o > 0; o >>= 1) sum += __shfl_xor(sum, o);
  __syncthreads();
  if (lane == 0) wred[wave] = sum;
  __syncthreads();
  float inv = 1.f / (wred[0] + wred[1] + wred[2] + wred[3]);

  // ---- PV ----
  {
    int d = tid & 63, s = tid >> 6;
    float acc = 0.f;
    const __bf16* vp = &Vb[((size_t)b * SEQ + s * 128) * DM + h * 64 + d];
#pragma unroll 8
    for (int k = 0; k < 128; ++k) acc += sc[s * 128 + k] * (float)vp[(size_t)k * DM];
    red[s][d] = acc;
  }
  __syncthreads();
  if (tid < 64)
    da[(size_t)b * DM + h * 64 + tid] =
        (red[0][tid] + red[1][tid] + red[2][tid] + red[3][tid]) * inv;
}

// x2 = LN2(da + t) recomputed per block; h = relu(x2@W1+b1); blk0 saves x2
__global__ __launch_bounds__(256) void dec_ffn1f(
    const float* __restrict__ da, const float* __restrict__ tbuf,
    const float* __restrict__ g2, const float* __restrict__ b2ln,
    const __bf16* __restrict__ W1T, const float* __restrict__ b1,
    float* __restrict__ h, float* __restrict__ xbuf) {
  __shared__ float a[8][DM];
  __shared__ float ps[4], pq[4];
  int tid = threadIdx.x, lane = tid & 63, wave = tid >> 6;
  for (int r = 0; r < 8; ++r) {
    float v0 = da[(size_t)r * DM + tid] + tbuf[(size_t)r * DM + tid];
    float v1 = da[(size_t)r * DM + tid + 256] + tbuf[(size_t)r * DM + tid + 256];
    ln_pair(v0, v1, tid, g2, b2ln, a[r], ps, pq);
  }
  int col = blockIdx.x * 4 + wave;
  bf16x8 w = *(const bf16x8*)&W1T[(size_t)col * DM + lane * 8];
  float acc[8];
#pragma unroll
  for (int r = 0; r < 8; ++r) acc[r] = dot8(w, &a[r][lane * 8]);
#pragma unroll
  for (int r = 0; r < 8; ++r)
    for (int o = 32; o > 0; o >>= 1) acc[r] += __shfl_xor(acc[r], o);
  if (lane == 0) {
    float bb = b1[col];
#pragma unroll
    for (int r = 0; r < 8; ++r) h[(size_t)r * DFF + col] = fmaxf(acc[r] + bb, 0.f);
  }
  if (blockIdx.x == 0) {
#pragma unroll
    for (int r = 0; r < 8; ++r) {
      xbuf[(size_t)r * DM + tid] = a[r][tid];
      xbuf[(size_t)r * DM + tid + 256] = a[r][tid + 256];
    }
  }
}

// df[r][col] = h[r] @ W2T[col] + b2[col]; 2 cols/block, 2 waves per col
__global__ __launch_bounds__(256) void dec_ffn2(
    const float* __restrict__ h, const __bf16* __restrict__ W2T,
    const float* __restrict__ b2, float* __restrict__ df) {
  __shared__ float red[4][8];
  int tid = threadIdx.x, lane = tid & 63, wave = tid >> 6;
  int c = wave >> 1, half = wave & 1;
  int col = blockIdx.x * 2 + c;
  int k0 = half * 1024 + lane * 8;
  bf16x8 w0 = *(const bf16x8*)&W2T[(size_t)col * DFF + k0];
  bf16x8 w1 = *(const bf16x8*)&W2T[(size_t)col * DFF + k0 + 512];
  float acc[8];
#pragma unroll
  for (int r = 0; r < 8; ++r) {
    float4 h0a = *(const float4*)&h[(size_t)r * DFF + k0];
    float4 h0b = *(const float4*)&h[(size_t)r * DFF + k0 + 4];
    float4 h1a = *(const float4*)&h[(size_t)r * DFF + k0 + 512];
    float4 h1b = *(const float4*)&h[(size_t)r * DFF + k0 + 516];
    float hh0[8] = {h0a.x, h0a.y, h0a.z, h0a.w, h0b.x, h0b.y, h0b.z, h0b.w};
    float hh1[8] = {h1a.x, h1a.y, h1a.z, h1a.w, h1b.x, h1b.y, h1b.z, h1b.w};
    acc[r] = dot8(w0, hh0) + dot8(w1, hh1);
  }
#pragma unroll
  for (int r = 0; r < 8; ++r)
    for (int o = 32; o > 0; o >>= 1) acc[r] += __shfl_xor(acc[r], o);
  if (lane == 0) {
#pragma unroll
    for (int r = 0; r < 8; ++r) red[wave][r] = acc[r];
  }
  __syncthreads();
  if (tid < 16) {
    int cc = tid >> 3, r = tid & 7;
    int ocol = blockIdx.x * 2 + cc;
    df[(size_t)r * DM + ocol] =
        red[cc * 2][r] + red[cc * 2 + 1][r] + b2[ocol];
  }
}

// out = LN3_5(df + x2) @ Wo + ob  (LN recomputed per block)
__global__ __launch_bounds__(256) void dec_outf(
    const float* __restrict__ df, const float* __restrict__ xbuf,
    const float* __restrict__ g3, const float* __restrict__ b3,
    const __bf16* __restrict__ WoT, const float* __restrict__ ob,
    float* __restrict__ out) {
  __shared__ float a[8][DM];
  __shared__ float ps[4], pq[4];
  int tid = threadIdx.x, lane = tid & 63, wave = tid >> 6;
  for (int r = 0; r < 8; ++r) {
    float v0 = df[(size_t)r * DM + tid] + xbuf[(size_t)r * DM + tid];
    float v1 = df[(size_t)r * DM + tid + 256] + xbuf[(size_t)r * DM + tid + 256];
    ln_pair(v0, v1, tid, g3, b3, a[r], ps, pq);
  }
  int col = blockIdx.x * 4 + wave;
  bf16x8 w = *(const bf16x8*)&WoT[(size_t)col * DM + lane * 8];
  float acc[8];
#pragma unroll
  for (int r = 0; r < 8; ++r) acc[r] = dot8(w, &a[r][lane * 8]);
#pragma unroll
  for (int r = 0; r < 8; ++r)
    for (int o = 32; o > 0; o >>= 1) acc[r] += __shfl_xor(acc[r], o);
  if (lane == 0) {
    float bb = ob[col];
#pragma unroll
    for (int r = 0; r < 8; ++r) out[(size_t)r * OUTD + col] = acc[r] + bb;
  }
}

// ---------------------------------------------------------------------------
extern "C" void kernel_launch(void* const* d_in, const int* in_sizes, int n_in,
                              void* d_out, int out_size, void* d_ws, size_t ws_size,
                              hipStream_t stream) {
  const int* x = (const int*)d_in[0];
  const int* target = (const int*)d_in[1];
  const float* in_emb = (const float*)d_in[2];
  const float* out_emb = (const float*)d_in[3];
  const float* enc_qkv_w = (const float*)d_in[4];
  const float* enc_qkv_b = (const float*)d_in[5];
  const float* enc_ln1_g = (const float*)d_in[6];
  const float* enc_ln1_b = (const float*)d_in[7];
  const float* enc_ffn1_w = (const float*)d_in[8];
  const float* enc_ffn1_b = (const float*)d_in[9];
  const float* enc_ffn2_w = (const float*)d_in[10];
  const float* enc_ffn2_b = (const float*)d_in[11];
  const float* enc_ln2_g = (const float*)d_in[12];
  const float* enc_ln2_b = (const float*)d_in[13];
  const float* dec_qkv1_w = (const float*)d_in[14];
  const float* dec_qkv1_b = (const float*)d_in[15];
  const float* dec_ln1_g = (const float*)d_in[16];
  const float* dec_ln1_b = (const float*)d_in[17];
  const float* dec_qkv2_w = (const float*)d_in[18];
  const float* dec_qkv2_b = (const float*)d_in[19];
  const float* dec_ln2_g = (const float*)d_in[20];
  const float* dec_ln2_b = (const float*)d_in[21];
  const float* dec_ffn1_w = (const float*)d_in[22];
  const float* dec_ffn1_b = (const float*)d_in[23];
  const float* dec_ffn2_w = (const float*)d_in[24];
  const float* dec_ffn2_b = (const float*)d_in[25];
  const float* dec_ln3_g = (const float*)d_in[26];
  const float* dec_ln3_b = (const float*)d_in[27];
  const float* out_w = (const float*)d_in[28];
  const float* out_b = (const float*)d_in[29];

  const long ACTL = (long)NB * SEQ * DM;           // 2M elems
  const int M = NB * SEQ;                           // 4096
  const long WQS = (long)DM * DM;
  const long WFS = (long)DM * DFF;

  char* p = (char*)d_ws;
  float* e = (float*)p;            p += ACTL * 4;
  float* tb = (float*)p;           p += ACTL * 4;
  float* pe = (float*)p;           p += (long)SEQ * DM * 4;
  float* dd = (float*)p;           p += NB * DM * 4;
  float* da = (float*)p;           p += NB * DM * 4;
  float* dh = (float*)p;           p += NB * DFF * 4;
  float* df = (float*)p;           p += NB * DM * 4;
  p = (char*)(((uintptr_t)p + 255) & ~(uintptr_t)255);
  __bf16* eb = (__bf16*)p;         p += ACTL * 2;
  __bf16* qkvb = (__bf16*)p;       p += 3 * ACTL * 2;   // Q,K; slice 2 = V^T
  __bf16* hbb = (__bf16*)p;        p += (long)M * DFF * 2;
  __bf16* kvb = (__bf16*)p;        p += 12L * ACTL * 2; // [layer][K,V][4096][512]
  __bf16* wtq = (__bf16*)p;        p += 18L * WQS * 2;
  __bf16* wtf1 = (__bf16*)p;       p += 6L * WFS * 2;
  __bf16* wtf2 = (__bf16*)p;       p += 6L * WFS * 2;
  __bf16* wtd = (__bf16*)p;        p += 18L * WQS * 2;  // dec_qkv2^T
  __bf16* wtd1 = (__bf16*)p;       p += 18L * WQS * 2;  // dec_qkv1 V-slices^T (6 used)
  __bf16* wf1t = (__bf16*)p;       p += 6L * WFS * 2;
  __bf16* wf2t = (__bf16*)p;       p += 6L * WFS * 2;
  __bf16* wot = (__bf16*)p;        p += (long)OUTD * DM * 2;

  __bf16* vtb = qkvb + 2 * ACTL;
  float* tb2 = (float*)kvb;      // FFN2 split-K partial-1 (kvb idle until KV gemm)
  float* tbuf = dd;
  float* xbuf = pe;

  // ---- one-time prep (merged transposes: 5 dispatches total) ----
  pe_kernel<<<SEQ, 256, 0, stream>>>(pe);
  transpose_w3<<<dim3(16, 16, 42), 256, 0, stream>>>(
      enc_qkv_w, wtq, 18, dec_qkv2_w, wtd, 18, dec_qkv1_w, wtd1, 3, 2, DM, DM);
  transpose_w3<<<dim3(64, 16, 12), 256, 0, stream>>>(
      enc_ffn1_w, wtf1, 6, dec_ffn1_w, wf1t, 6, nullptr, nullptr, 0, 0, DM, DFF);
  transpose_w3<<<dim3(16, 64, 12), 256, 0, stream>>>(
      enc_ffn2_w, wtf2, 6, dec_ffn2_w, wf2t, 6, nullptr, nullptr, 0, 0, DFF, DM);
  transpose_ow<<<dim3(32, 16), 256, 0, stream>>>(out_w, wot);

  // ---- encoder ----
  embed_enc<<<(M * DM / 2) / 256, 256, 0, stream>>>(x, in_emb, pe, e, eb);
  for (int i = 0; i < NL; ++i) {
    mfma_gemm<64, 1, false, false, true, true, false><<<dim3(8, 32, 3), 256, 0, stream>>>(
        eb, wtq + (size_t)i * 3 * WQS, enc_qkv_b + (size_t)i * 3 * DM,
        nullptr, qkvb, vtb, M, DM, DM, WQS, DM, ACTL);
    attn_mfma<<<dim3(SEQ / 16, NB * NH), 256, 0, stream>>>(qkvb, vtb, tb);
    add_ln<true><<<M, 256, 0, stream>>>(tb, nullptr, e, nullptr,
                                        enc_ln1_g + i * DM, enc_ln1_b + i * DM,
                                        e, eb);
    mfma_gemm<64, 1, true, false, true, false, false><<<dim3(32, 32, 1), 256, 0, stream>>>(
        eb, wtf1 + (size_t)i * WFS, enc_ffn1_b + (size_t)i * DFF,
        nullptr, hbb, nullptr, M, DFF, DM, 0, 0, 0);
    mfma_gemm<64, 2, false, true, false, false, false><<<dim3(8, 32, 2), 256, 0, stream>>>(
        hbb, wtf2 + (size_t)i * WFS, enc_ffn2_b + (size_t)i * DM,
        tb, nullptr, nullptr, M, DM, DFF, 0, 0, (long)(tb2 - tb));
    add_ln<true><<<M, 256, 0, stream>>>(tb, tb2, e, nullptr,
                                        enc_ln2_g + i * DM, enc_ln2_b + i * DM,
                                        e, eb);
  }

  // ---- cross K/V for all 6 layers in one dispatch (bf16 out) ----
  mfma_gemm<64, 1, false, false, true, false, true><<<dim3(8, 32, 12), 256, 0, stream>>>(
      eb, wtd, dec_qkv2_b, nullptr, kvb, nullptr, M, DM, DM, WQS, DM, ACTL);

  // ---- decoder: 3 dispatches per layer ----
  for (int i = 0; i < NL; ++i) {
    const __bf16* Wv = wtd1 + (size_t)i * WQS;
    const float* bvp = dec_qkv1_b + ((size_t)i * 3 + 2) * DM;
    const __bf16* Wq = wtd + (size_t)i * 3 * WQS;
    const float* qbp = dec_qkv2_b + (size_t)i * 3 * DM;
    const __bf16* Kb = kvb + (size_t)i * 2 * ACTL;
    const __bf16* Vb = kvb + ((size_t)i * 2 + 1) * ACTL;
    if (i == 0)
      dec_attn<true><<<64, 256, 0, stream>>>(
          nullptr, nullptr, nullptr, nullptr, target, out_emb,
          Wv, bvp, dec_ln1_g + i * DM, dec_ln1_b + i * DM,
          Wq, qbp, Kb, Vb, da, tbuf);
    else
      dec_attn<false><<<64, 256, 0, stream>>>(
          df, xbuf, dec_ln3_g + (i - 1) * DM, dec_ln3_b + (i - 1) * DM,
          nullptr, nullptr,
          Wv, bvp, dec_ln1_g + i * DM, dec_ln1_b + i * DM,
          Wq, qbp, Kb, Vb, da, tbuf);
    dec_ffn1f<<<DFF / 4, 256, 0, stream>>>(
        da, tbuf, dec_ln2_g + i * DM, dec_ln2_b + i * DM,
        wf1t + (size_t)i * WFS, dec_ffn1_b + (size_t)i * DFF, dh, xbuf);
    dec_ffn2<<<DM / 2, 256, 0, stream>>>(
        dh, wf2t + (size_t)i * WFS, dec_ffn2_b + (size_t)i * DM, df);
  }

  // ---- output projection (LN3 + gemv + bias fused) ----
  dec_outf<<<OUTD / 4, 256, 0, stream>>>(df, xbuf, dec_ln3_g + 5 * DM,
                                         dec_ln3_b + 5 * DM, wot, out_b,
                                         (float*)d_out);
}

// Round 9
// 1154.697 us; speedup vs baseline: 1.3466x; 1.3466x over previous
//
#include <hip/hip_runtime.h>
#include <hip/hip_bf16.h>

#define DM 512
#define NH 8
#define DK 64
#define SEQ 512
#define NB 8
#define NL 6
#define DFF 2048
#define OUTD 1000
#define EMB_SCALE 22.627416997969522f
#define PE_C (-0.017988946039015984f)   // -ln(10000)/512

typedef __bf16 bf16x8 __attribute__((ext_vector_type(8)));
typedef __bf16 bf16x4 __attribute__((ext_vector_type(4)));
typedef float f32x4 __attribute__((ext_vector_type(4)));

__device__ __forceinline__ void load16_lds(const __bf16* g, __bf16* l) {
  __builtin_amdgcn_global_load_lds(
      (const __attribute__((address_space(1))) void*)g,
      (__attribute__((address_space(3))) void*)l, 16, 0, 0);
}

__device__ __forceinline__ float dot8(bf16x8 w, const float* a) {
  float s = 0.f;
#pragma unroll
  for (int j = 0; j < 8; ++j) s += (float)w[j] * a[j];
  return s;
}

// block-wide LN over a 512-elem row held as (v0 @ tid, v1 @ tid+256).
__device__ __forceinline__ void ln_pair(float v0, float v1, int tid,
                                        const float* __restrict__ g,
                                        const float* __restrict__ beta,
                                        float* out, float* ps, float* pq) {
  float s = v0 + v1, sq = v0 * v0 + v1 * v1;
  for (int o = 32; o > 0; o >>= 1) { s += __shfl_xor(s, o); sq += __shfl_xor(sq, o); }
  int wv = tid >> 6;
  if ((tid & 63) == 0) { ps[wv] = s; pq[wv] = sq; }
  __syncthreads();
  s = ps[0] + ps[1] + ps[2] + ps[3];
  sq = pq[0] + pq[1] + pq[2] + pq[3];
  float mean = s * (1.f / DM);
  float rstd = rsqrtf(sq * (1.f / DM) - mean * mean + 1e-5f);
  out[tid] = (v0 - mean) * rstd * g[tid] + beta[tid];
  out[tid + 256] = (v1 - mean) * rstd * g[tid + 256] + beta[tid + 256];
  __syncthreads();
}

// ---------------- PE table ----------------
__global__ __launch_bounds__(256) void pe_kernel(float* __restrict__ pe) {
  int s = blockIdx.x;
  int d2 = threadIdx.x;
  float div = expf((float)(2 * d2) * PE_C);
  float arg = (float)s * div;
  pe[(size_t)s * DM + 2 * d2] = sinf(arg);
  pe[(size_t)s * DM + 2 * d2 + 1] = cosf(arg);
}

// ---------------- embedding (float2 vectorized) ----------------
__global__ __launch_bounds__(256) void embed_enc(const int* __restrict__ x,
                                                 const float* __restrict__ emb,
                                                 const float* __restrict__ pe,
                                                 float* __restrict__ e,
                                                 __bf16* __restrict__ eb) {
  int idx = blockIdx.x * 256 + threadIdx.x;   // 2-elem granule index
  int d2 = idx & 255;
  int bs = idx >> 8;
  int s = bs & (SEQ - 1);
  int tok = x[bs];
  float2 ev = ((const float2*)(emb + (size_t)tok * DM))[d2];
  float2 pv = ((const float2*)(pe + (size_t)s * DM))[d2];
  float v0 = ev.x * EMB_SCALE + pv.x;
  float v1 = ev.y * EMB_SCALE + pv.y;
  ((float2*)e)[idx] = make_float2(v0, v1);
  union { __bf16 h[2]; unsigned u; } pk;
  pk.h[0] = (__bf16)v0; pk.h[1] = (__bf16)v1;
  ((unsigned*)eb)[idx] = pk.u;
}

// ---------------- merged weight transpose fp32[K][N] -> bf16[N][K] ---------
__global__ __launch_bounds__(256) void transpose_w3(
    const float* __restrict__ W0, __bf16* __restrict__ T0, int n0,
    const float* __restrict__ W1, __bf16* __restrict__ T1, int n1,
    const float* __restrict__ W2, __bf16* __restrict__ T2,
    long zmul2, long zadd2, int K, int N) {
  __shared__ float t[32][33];
  int z = blockIdx.z;
  const float* W;
  __bf16* WT;
  if (z < n0) {
    W = W0 + (size_t)z * K * N; WT = T0 + (size_t)z * K * N;
  } else if (z < n0 + n1) {
    int zz = z - n0;
    W = W1 + (size_t)zz * K * N; WT = T1 + (size_t)zz * K * N;
  } else {
    int zz = z - n0 - n1;
    W = W2 + (size_t)(zz * zmul2 + zadd2) * K * N;
    WT = T2 + (size_t)zz * K * N;
  }
  int k0 = blockIdx.y * 32, n0b = blockIdx.x * 32;
  int tx = threadIdx.x & 7, ty = threadIdx.x >> 3;
  float4 v = *(const float4*)&W[(size_t)(k0 + ty) * N + n0b + tx * 4];
  t[ty][tx * 4 + 0] = v.x; t[ty][tx * 4 + 1] = v.y;
  t[ty][tx * 4 + 2] = v.z; t[ty][tx * 4 + 3] = v.w;
  __syncthreads();
  bf16x4 o;
  o[0] = (__bf16)t[tx * 4 + 0][ty];
  o[1] = (__bf16)t[tx * 4 + 1][ty];
  o[2] = (__bf16)t[tx * 4 + 2][ty];
  o[3] = (__bf16)t[tx * 4 + 3][ty];
  *(bf16x4*)&WT[(size_t)(n0b + ty) * K + k0 + tx * 4] = o;
}

// out_w fp32 [512][1000] -> bf16 [1000][512] (guarded tail)
__global__ __launch_bounds__(256) void transpose_ow(const float* __restrict__ W,
                                                    __bf16* __restrict__ WT) {
  __shared__ float t[32][33];
  int n0 = blockIdx.x * 32, k0 = blockIdx.y * 32;
  int tid = threadIdx.x;
  for (int i = tid; i < 1024; i += 256) {
    int kk = i >> 5, nn = i & 31;
    t[kk][nn] = (n0 + nn < OUTD) ? W[(size_t)(k0 + kk) * OUTD + n0 + nn] : 0.f;
  }
  __syncthreads();
  for (int i = tid; i < 1024; i += 256) {
    int nn = i >> 5, kk = i & 31;
    if (n0 + nn < OUTD)
      WT[(size_t)(n0 + nn) * DM + k0 + kk] = (__bf16)t[kk][nn];
  }
}

// ---------------- MFMA GEMM: 256 thr / 4 waves, BM=128 x BN=64 tiles,
// per-wave 64x32 output (acc[4][2]), dbuf staging (T3 2-phase), XCD swizzle.
// LDS 48KB -> 3 blocks/CU. R3 structure — confirmed local optimum for these
// skinny-N shapes (R1 dbuf, R4 deep-pipeline, R8 A-direct all regressed).
template <int BN, int SK, bool RELU, bool WF32, bool WBF16, bool TRV, bool KVM>
__global__ __launch_bounds__(256) void mfma_gemm(
    const __bf16* __restrict__ A, const __bf16* __restrict__ BT,
    const float* __restrict__ bias, float* __restrict__ C,
    __bf16* __restrict__ Cb, __bf16* __restrict__ Vt, int M, int N, int K,
    long btStride, long bStride, long cStride) {
  // XCD swizzle: each XCD owns a contiguous y-chunk; x fastest, z slowest.
  int gx = gridDim.x, gy = gridDim.y;
  int lin = blockIdx.x + gx * (blockIdx.y + gy * blockIdx.z);
  int xcd = lin & 7, li = lin >> 3;
  int yc = gy >> 3;
  int bx = li % gx;
  int t2 = li / gx;
  int by = xcd * yc + (t2 % yc);
  int z = t2 / yc;

  if (SK == 1) {
    if (KVM) {
      long idx = (long)(z >> 1) * 3 + 1 + (z & 1);
      BT += idx * btStride;
      bias += idx * bStride;
    } else {
      BT += (size_t)z * btStride;
      bias += (size_t)z * bStride;
    }
  }
  if (WF32) C += (size_t)z * cStride;
  if (WBF16) Cb += (size_t)z * cStride;

  constexpr int NI = BN / 32;
  __shared__ __bf16 As[2][128 * 64];
  __shared__ __bf16 Bs[2][BN * 64];

  int tid = threadIdx.x;
  int wave = tid >> 6, lane = tid & 63;
  int wm = wave >> 1, wn = wave & 1;           // 2 x 2 wave grid
  int quad = lane >> 4, l16 = lane & 15;
  int rlane = lane >> 3, c8 = lane & 7;
  int m0 = by * 128, n0 = bx * BN;
  int gcol = ((c8 ^ rlane) * 8);

  f32x4 acc[4][NI];
#pragma unroll
  for (int i = 0; i < 4; ++i)
#pragma unroll
    for (int j = 0; j < NI; ++j) acc[i][j] = (f32x4){0.f, 0.f, 0.f, 0.f};

  auto stage = [&](int buf, int k0) {
#pragma unroll
    for (int j = 0; j < 4; ++j) {
      int rb = j * 32 + wave * 8;
      load16_lds(&A[(size_t)(m0 + rb + rlane) * K + k0 + gcol],
                 &As[buf][rb * 64]);
    }
#pragma unroll
    for (int j = 0; j < BN / 32; ++j) {
      int rb = j * 32 + wave * 8;
      load16_lds(&BT[(size_t)(n0 + rb + rlane) * K + k0 + gcol],
                 &Bs[buf][rb * 64]);
    }
  };

  int kLen = (SK > 1) ? (K / SK) : K;
  int kBeg = (SK > 1) ? z * kLen : 0;
  const int NT = kLen >> 6;
  stage(0, kBeg);
  __syncthreads();
  for (int t = 0; t < NT; ++t) {
    int cur = t & 1;
    if (t + 1 < NT) stage(cur ^ 1, kBeg + ((t + 1) << 6));
#pragma unroll
    for (int kk = 0; kk < 64; kk += 32) {
      bf16x8 af[4], bfr[NI];
#pragma unroll
      for (int i = 0; i < 4; ++i) {
        int row = wm * 64 + i * 16 + l16;
        af[i] = *(const bf16x8*)&As[cur][row * 64 + ((((kk >> 3) + quad) ^ (row & 7)) * 8)];
      }
#pragma unroll
      for (int i = 0; i < NI; ++i) {
        int row = wn * (BN / 2) + i * 16 + l16;
        bfr[i] = *(const bf16x8*)&Bs[cur][row * 64 + ((((kk >> 3) + quad) ^ (row & 7)) * 8)];
      }
#pragma unroll
      for (int mi = 0; mi < 4; ++mi)
#pragma unroll
        for (int ni = 0; ni < NI; ++ni)
          acc[mi][ni] = __builtin_amdgcn_mfma_f32_16x16x32_bf16(
              af[mi], bfr[ni], acc[mi][ni], 0, 0, 0);
    }
    __syncthreads();
  }

#pragma unroll
  for (int ni = 0; ni < NI; ++ni) {
    int col = n0 + wn * (BN / 2) + ni * 16 + l16;
    float bv = (SK == 1 || z == 0) ? bias[col] : 0.f;
    if (TRV && z == 2) {
      int b = m0 >> 9;
#pragma unroll
      for (int mi = 0; mi < 4; ++mi) {
        int srow = (m0 & 511) + wm * 64 + mi * 16 + quad * 4;
        bf16x4 pk;
#pragma unroll
        for (int r = 0; r < 4; ++r) pk[r] = (__bf16)(acc[mi][ni][r] + bv);
        *(bf16x4*)&Vt[((size_t)(b * 512 + col)) * 512 + srow] = pk;
      }
    } else {
#pragma unroll
      for (int mi = 0; mi < 4; ++mi) {
#pragma unroll
        for (int r = 0; r < 4; ++r) {
          int row = m0 + wm * 64 + mi * 16 + quad * 4 + r;
          float v = acc[mi][ni][r] + bv;
          if (RELU) v = fmaxf(v, 0.f);
          if (WF32) C[(size_t)row * N + col] = v;
          if (WBF16) Cb[(size_t)row * N + col] = (__bf16)v;
        }
      }
    }
  }
}

// ---------------- MFMA encoder attention: zero K/V staging -----------------
// K/V panels per (b,h) are 64KB and L2-resident across the 32 blocks sharing
// them (m169 criterion). Fragments read directly from global; LDS is Sc only
// (16.6KB) -> 8 blocks/CU (32 waves) vs 3 with staging; TLP absorbs L2
// latency. Only 2 barriers per block (around softmax).
#define SCP 520
__global__ __launch_bounds__(256) void attn_mfma(const __bf16* __restrict__ QKV,
                                                 const __bf16* __restrict__ Vt,
                                                 float* __restrict__ O) {
  __shared__ __bf16 Sc[16 * SCP];

  const long ACTL = (long)NB * SEQ * DM;
  int tid = threadIdx.x;
  int wave = tid >> 6, lane = tid & 63;
  int quad = lane >> 4, l16 = lane & 15;
  // XCD swizzle: chunk by bh so each XCD's L2 holds few K/V panels.
  int lin = blockIdx.x + gridDim.x * blockIdx.y;
  int xcd = lin & 7, li = lin >> 3;
  int yc = gridDim.y >> 3;
  int q0 = (li % gridDim.x) * 16;
  int bh = xcd * yc + li / gridDim.x;
  int b = bh >> 3, h = bh & 7;
  const __bf16* Q = QKV;
  const __bf16* Kp = QKV + ACTL;
  size_t baseQ = ((size_t)b * SEQ + q0) * DM + h * DK;
  size_t baseK = ((size_t)b * SEQ) * DM + h * DK;
  const __bf16* VtB = Vt + ((size_t)(b * 512 + h * 64)) * 512;

  bf16x8 af0 = *(const bf16x8*)&Q[baseQ + (size_t)l16 * DM + quad * 8];
  bf16x8 af1 = *(const bf16x8*)&Q[baseQ + (size_t)l16 * DM + 32 + quad * 8];

  // ---- QK^T, 8 tiles, direct K reads, no barriers ----
  int krow = wave * 16 + l16;
#pragma unroll 2
  for (int kt = 0; kt < 8; ++kt) {
    const __bf16* kp = &Kp[baseK + (size_t)(kt * 64 + krow) * DM];
    bf16x8 b0 = *(const bf16x8*)&kp[quad * 8];
    bf16x8 b1 = *(const bf16x8*)&kp[32 + quad * 8];
    f32x4 acc = (f32x4){0.f, 0.f, 0.f, 0.f};
    acc = __builtin_amdgcn_mfma_f32_16x16x32_bf16(af0, b0, acc, 0, 0, 0);
    acc = __builtin_amdgcn_mfma_f32_16x16x32_bf16(af1, b1, acc, 0, 0, 0);
#pragma unroll
    for (int r = 0; r < 4; ++r)
      Sc[(quad * 4 + r) * SCP + kt * 64 + wave * 16 + l16] =
          (__bf16)(acc[r] * 0.125f);
  }
  __syncthreads();

  // ---- softmax over 16 rows ----
#pragma unroll
  for (int rr = 0; rr < 4; ++rr) {
    int r = wave * 4 + rr;
    float v[8];
    float mx = -1e30f;
#pragma unroll
    for (int j = 0; j < 8; ++j) {
      v[j] = (float)Sc[r * SCP + j * 64 + lane];
      mx = fmaxf(mx, v[j]);
    }
    for (int o = 32; o > 0; o >>= 1) mx = fmaxf(mx, __shfl_xor(mx, o));
    float sum = 0.f;
#pragma unroll
    for (int j = 0; j < 8; ++j) { v[j] = __expf(v[j] - mx); sum += v[j]; }
    for (int o = 32; o > 0; o >>= 1) sum += __shfl_xor(sum, o);
    float inv = 1.f / sum;
#pragma unroll
    for (int j = 0; j < 8; ++j)
      Sc[r * SCP + j * 64 + lane] = (__bf16)(v[j] * inv);
  }
  __syncthreads();

  // ---- PV, 8 tiles, direct V^T reads, no barriers ----
  f32x4 oacc = (f32x4){0.f, 0.f, 0.f, 0.f};
  int drow = wave * 16 + l16;
#pragma unroll 2
  for (int kt = 0; kt < 8; ++kt) {
#pragma unroll
    for (int kk = 0; kk < 64; kk += 32) {
      bf16x8 pa = *(const bf16x8*)&Sc[l16 * SCP + kt * 64 + kk + quad * 8];
      bf16x8 vb = *(const bf16x8*)&VtB[(size_t)drow * 512 + kt * 64 + kk + quad * 8];
      oacc = __builtin_amdgcn_mfma_f32_16x16x32_bf16(pa, vb, oacc, 0, 0, 0);
    }
  }
#pragma unroll
  for (int r = 0; r < 4; ++r)
    O[((size_t)b * SEQ + q0 + quad * 4 + r) * DM + h * DK + wave * 16 + l16] =
        oacc[r];
}

// ---------------- residual + layernorm (float2 vectorized) -------
template <bool WB>
__global__ __launch_bounds__(256) void add_ln(
    const float* __restrict__ x, const float* __restrict__ x2,
    const float* __restrict__ res, const float* __restrict__ cbias,
    const float* __restrict__ g, const float* __restrict__ beta,
    float* __restrict__ y, __bf16* __restrict__ yb) {
  int row = blockIdx.x;
  int tid = threadIdx.x;                // one float2 (cols 2t,2t+1) per thread
  float2 xv = ((const float2*)(x + (size_t)row * DM))[tid];
  float2 rv = ((const float2*)(res + (size_t)row * DM))[tid];
  float v0 = xv.x + rv.x;
  float v1 = xv.y + rv.y;
  if (cbias) {
    float2 cb = ((const float2*)cbias)[tid];
    v0 += cb.x; v1 += cb.y;
  }
  if (x2) {
    float2 x2v = ((const float2*)(x2 + (size_t)row * DM))[tid];
    v0 += x2v.x; v1 += x2v.y;
  }
  float s = v0 + v1, sq = v0 * v0 + v1 * v1;
  for (int o = 32; o > 0; o >>= 1) {
    s += __shfl_xor(s, o);
    sq += __shfl_xor(sq, o);
  }
  __shared__ float ps[4], pq[4];
  int wv = tid >> 6;
  if ((tid & 63) == 0) { ps[wv] = s; pq[wv] = sq; }
  __syncthreads();
  s = ps[0] + ps[1] + ps[2] + ps[3];
  sq = pq[0] + pq[1] + pq[2] + pq[3];
  float mean = s * (1.f / DM);
  float var = sq * (1.f / DM) - mean * mean;
  float rstd = rsqrtf(var + 1e-5f);
  float2 gg = ((const float2*)g)[tid];
  float2 bb = ((const float2*)beta)[tid];
  float o0 = (v0 - mean) * rstd * gg.x + bb.x;
  float o1 = (v1 - mean) * rstd * gg.y + bb.y;
  ((float2*)(y + (size_t)row * DM))[tid] = make_float2(o0, o1);
  if (WB) {
    union { __bf16 h[2]; unsigned u; } pk;
    pk.h[0] = (__bf16)o0; pk.h[1] = (__bf16)o1;
    ((unsigned*)(yb + (size_t)row * DM))[tid] = pk.u;
  }
}

// ============ fused decoder (3 dispatches/layer) ============

// one block per (b,h); LN1/LN3 recomputed redundantly per block (cheap)
template <bool FIRST>
__global__ __launch_bounds__(256) void dec_attn(
    const float* __restrict__ dfp, const float* __restrict__ xp,
    const float* __restrict__ g3, const float* __restrict__ b3,
    const int* __restrict__ target, const float* __restrict__ emb,
    const __bf16* __restrict__ WvT, const float* __restrict__ bv,
    const float* __restrict__ g1, const float* __restrict__ b1ln,
    const __bf16* __restrict__ WqT, const float* __restrict__ qb,
    const __bf16* __restrict__ Kb, const __bf16* __restrict__ Vb,
    float* __restrict__ da, float* __restrict__ tbuf) {
  __shared__ float arow[DM];
  __shared__ float trow[DM];
  __shared__ float red[4][64];
  __shared__ float q[64];
  __shared__ float sc[SEQ];
  __shared__ float wred[4];
  __shared__ float ps[4], pq[4];

  int bh = blockIdx.x, b = bh >> 3, h = bh & 7;
  int tid = threadIdx.x, lane = tid & 63, wave = tid >> 6;

  // ---- dd (layer input) ----
  if (FIRST) {
    int tok = target[b];
    arow[tid] = emb[(size_t)tok * DM + tid] * EMB_SCALE + ((tid & 1) ? 1.f : 0.f);
    arow[tid + 256] =
        emb[(size_t)tok * DM + tid + 256] * EMB_SCALE + ((tid & 1) ? 1.f : 0.f);
    __syncthreads();
  } else {
    float v0 = dfp[(size_t)b * DM + tid] + xp[(size_t)b * DM + tid];
    float v1 = dfp[(size_t)b * DM + tid + 256] + xp[(size_t)b * DM + tid + 256];
    ln_pair(v0, v1, tid, g3, b3, arow, ps, pq);
  }

  // ---- t = LN1(dd + dd@Wv + bv) ----
  float o0, o1;
  {
    const __bf16* w = &WvT[(size_t)tid * DM];
    float acc = 0.f;
#pragma unroll 4
    for (int k = 0; k < DM; k += 8) acc += dot8(*(const bf16x8*)&w[k], &arow[k]);
    o0 = arow[tid] + acc + bv[tid];
  }
  {
    const __bf16* w = &WvT[(size_t)(tid + 256) * DM];
    float acc = 0.f;
#pragma unroll 4
    for (int k = 0; k < DM; k += 8) acc += dot8(*(const bf16x8*)&w[k], &arow[k]);
    o1 = arow[tid + 256] + acc + bv[tid + 256];
  }
  ln_pair(o0, o1, tid, g1, b1ln, trow, ps, pq);
  if (h == 0) {
    tbuf[(size_t)b * DM + tid] = trow[tid];
    tbuf[(size_t)b * DM + tid + 256] = trow[tid + 256];
  }

  // ---- q-gemv: 64 cols x 4 k-subs from trow ----
  {
    int c = tid & 63, s = tid >> 6;
    const __bf16* w = &WqT[(size_t)(h * 64 + c) * DM + s * 128];
    float acc = 0.f;
#pragma unroll
    for (int k = 0; k < 128; k += 8)
      acc += dot8(*(const bf16x8*)&w[k], &trow[s * 128 + k]);
    red[s][c] = acc;
  }
  __syncthreads();
  if (tid < 64)
    q[tid] = red[0][tid] + red[1][tid] + red[2][tid] + red[3][tid] + qb[h * 64 + tid];
  __syncthreads();

  // ---- scores ----
  for (int key = tid; key < SEQ; key += 256) {
    const __bf16* kp = &Kb[((size_t)b * SEQ + key) * DM + h * 64];
    float acc = 0.f;
#pragma unroll
    for (int k = 0; k < 64; k += 8) acc += dot8(*(const bf16x8*)&kp[k], &q[k]);
    sc[key] = acc * 0.125f;
  }
  __syncthreads();
  float m = -1e30f;
  for (int j = tid; j < SEQ; j += 256) m = fmaxf(m, sc[j]);
  for (int o = 32; o > 0; o >>= 1) m = fmaxf(m, __shfl_xor(m, o));
  if (lane == 0) wred[wave] = m;
  __syncthreads();
  m = fmaxf(fmaxf(wred[0], wred[1]), fmaxf(wred[2], wred[3]));
  float sum = 0.f;
  for (int j = tid; j < SEQ; j += 256) {
    float p = __expf(sc[j] - m);
    sc[j] = p;
    sum += p;
  }
  for (int o = 32; o > 0; o >>= 1) sum += __shfl_xor(sum, o);
  __syncthreads();
  if (lane == 0) wred[wave] = sum;
  __syncthreads();
  float inv = 1.f / (wred[0] + wred[1] + wred[2] + wred[3]);

  // ---- PV ----
  {
    int d = tid & 63, s = tid >> 6;
    float acc = 0.f;
    const __bf16* vp = &Vb[((size_t)b * SEQ + s * 128) * DM + h * 64 + d];
#pragma unroll 8
    for (int k = 0; k < 128; ++k) acc += sc[s * 128 + k] * (float)vp[(size_t)k * DM];
    red[s][d] = acc;
  }
  __syncthreads();
  if (tid < 64)
    da[(size_t)b * DM + h * 64 + tid] =
        (red[0][tid] + red[1][tid] + red[2][tid] + red[3][tid]) * inv;
}

// x2 = LN2(da + t) recomputed per block; h = relu(x2@W1+b1); blk0 saves x2
__global__ __launch_bounds__(256) void dec_ffn1f(
    const float* __restrict__ da, const float* __restrict__ tbuf,
    const float* __restrict__ g2, const float* __restrict__ b2ln,
    const __bf16* __restrict__ W1T, const float* __restrict__ b1,
    float* __restrict__ h, float* __restrict__ xbuf) {
  __shared__ float a[8][DM];
  __shared__ float ps[4], pq[4];
  int tid = threadIdx.x, lane = tid & 63, wave = tid >> 6;
  for (int r = 0; r < 8; ++r) {
    float v0 = da[(size_t)r * DM + tid] + tbuf[(size_t)r * DM + tid];
    float v1 = da[(size_t)r * DM + tid + 256] + tbuf[(size_t)r * DM + tid + 256];
    ln_pair(v0, v1, tid, g2, b2ln, a[r], ps, pq);
  }
  int col = blockIdx.x * 4 + wave;
  bf16x8 w = *(const bf16x8*)&W1T[(size_t)col * DM + lane * 8];
  float acc[8];
#pragma unroll
  for (int r = 0; r < 8; ++r) acc[r] = dot8(w, &a[r][lane * 8]);
#pragma unroll
  for (int r = 0; r < 8; ++r)
    for (int o = 32; o > 0; o >>= 1) acc[r] += __shfl_xor(acc[r], o);
  if (lane == 0) {
    float bb = b1[col];
#pragma unroll
    for (int r = 0; r < 8; ++r) h[(size_t)r * DFF + col] = fmaxf(acc[r] + bb, 0.f);
  }
  if (blockIdx.x == 0) {
#pragma unroll
    for (int r = 0; r < 8; ++r) {
      xbuf[(size_t)r * DM + tid] = a[r][tid];
      xbuf[(size_t)r * DM + tid + 256] = a[r][tid + 256];
    }
  }
}

// df[r][col] = h[r] @ W2T[col] + b2[col]; 2 cols/block, 2 waves per col
__global__ __launch_bounds__(256) void dec_ffn2(
    const float* __restrict__ h, const __bf16* __restrict__ W2T,
    const float* __restrict__ b2, float* __restrict__ df) {
  __shared__ float red[4][8];
  int tid = threadIdx.x, lane = tid & 63, wave = tid >> 6;
  int c = wave >> 1, half = wave & 1;
  int col = blockIdx.x * 2 + c;
  int k0 = half * 1024 + lane * 8;
  bf16x8 w0 = *(const bf16x8*)&W2T[(size_t)col * DFF + k0];
  bf16x8 w1 = *(const bf16x8*)&W2T[(size_t)col * DFF + k0 + 512];
  float acc[8];
#pragma unroll
  for (int r = 0; r < 8; ++r) {
    float4 h0a = *(const float4*)&h[(size_t)r * DFF + k0];
    float4 h0b = *(const float4*)&h[(size_t)r * DFF + k0 + 4];
    float4 h1a = *(const float4*)&h[(size_t)r * DFF + k0 + 512];
    float4 h1b = *(const float4*)&h[(size_t)r * DFF + k0 + 516];
    float hh0[8] = {h0a.x, h0a.y, h0a.z, h0a.w, h0b.x, h0b.y, h0b.z, h0b.w};
    float hh1[8] = {h1a.x, h1a.y, h1a.z, h1a.w, h1b.x, h1b.y, h1b.z, h1b.w};
    acc[r] = dot8(w0, hh0) + dot8(w1, hh1);
  }
#pragma unroll
  for (int r = 0; r < 8; ++r)
    for (int o = 32; o > 0; o >>= 1) acc[r] += __shfl_xor(acc[r], o);
  if (lane == 0) {
#pragma unroll
    for (int r = 0; r < 8; ++r) red[wave][r] = acc[r];
  }
  __syncthreads();
  if (tid < 16) {
    int cc = tid >> 3, r = tid & 7;
    int ocol = blockIdx.x * 2 + cc;
    df[(size_t)r * DM + ocol] =
        red[cc * 2][r] + red[cc * 2 + 1][r] + b2[ocol];
  }
}

// out = LN3_5(df + x2) @ Wo + ob  (LN recomputed per block)
__global__ __launch_bounds__(256) void dec_outf(
    const float* __restrict__ df, const float* __restrict__ xbuf,
    const float* __restrict__ g3, const float* __restrict__ b3,
    const __bf16* __restrict__ WoT, const float* __restrict__ ob,
    float* __restrict__ out) {
  __shared__ float a[8][DM];
  __shared__ float ps[4], pq[4];
  int tid = threadIdx.x, lane = tid & 63, wave = tid >> 6;
  for (int r = 0; r < 8; ++r) {
    float v0 = df[(size_t)r * DM + tid] + xbuf[(size_t)r * DM + tid];
    float v1 = df[(size_t)r * DM + tid + 256] + xbuf[(size_t)r * DM + tid + 256];
    ln_pair(v0, v1, tid, g3, b3, a[r], ps, pq);
  }
  int col = blockIdx.x * 4 + wave;
  bf16x8 w = *(const bf16x8*)&WoT[(size_t)col * DM + lane * 8];
  float acc[8];
#pragma unroll
  for (int r = 0; r < 8; ++r) acc[r] = dot8(w, &a[r][lane * 8]);
#pragma unroll
  for (int r = 0; r < 8; ++r)
    for (int o = 32; o > 0; o >>= 1) acc[r] += __shfl_xor(acc[r], o);
  if (lane == 0) {
    float bb = ob[col];
#pragma unroll
    for (int r = 0; r < 8; ++r) out[(size_t)r * OUTD + col] = acc[r] + bb;
  }
}

// ---------------------------------------------------------------------------
extern "C" void kernel_launch(void* const* d_in, const int* in_sizes, int n_in,
                              void* d_out, int out_size, void* d_ws, size_t ws_size,
                              hipStream_t stream) {
  const int* x = (const int*)d_in[0];
  const int* target = (const int*)d_in[1];
  const float* in_emb = (const float*)d_in[2];
  const float* out_emb = (const float*)d_in[3];
  const float* enc_qkv_w = (const float*)d_in[4];
  const float* enc_qkv_b = (const float*)d_in[5];
  const float* enc_ln1_g = (const float*)d_in[6];
  const float* enc_ln1_b = (const float*)d_in[7];
  const float* enc_ffn1_w = (const float*)d_in[8];
  const float* enc_ffn1_b = (const float*)d_in[9];
  const float* enc_ffn2_w = (const float*)d_in[10];
  const float* enc_ffn2_b = (const float*)d_in[11];
  const float* enc_ln2_g = (const float*)d_in[12];
  const float* enc_ln2_b = (const float*)d_in[13];
  const float* dec_qkv1_w = (const float*)d_in[14];
  const float* dec_qkv1_b = (const float*)d_in[15];
  const float* dec_ln1_g = (const float*)d_in[16];
  const float* dec_ln1_b = (const float*)d_in[17];
  const float* dec_qkv2_w = (const float*)d_in[18];
  const float* dec_qkv2_b = (const float*)d_in[19];
  const float* dec_ln2_g = (const float*)d_in[20];
  const float* dec_ln2_b = (const float*)d_in[21];
  const float* dec_ffn1_w = (const float*)d_in[22];
  const float* dec_ffn1_b = (const float*)d_in[23];
  const float* dec_ffn2_w = (const float*)d_in[24];
  const float* dec_ffn2_b = (const float*)d_in[25];
  const float* dec_ln3_g = (const float*)d_in[26];
  const float* dec_ln3_b = (const float*)d_in[27];
  const float* out_w = (const float*)d_in[28];
  const float* out_b = (const float*)d_in[29];

  const long ACTL = (long)NB * SEQ * DM;           // 2M elems
  const int M = NB * SEQ;                           // 4096
  const long WQS = (long)DM * DM;
  const long WFS = (long)DM * DFF;

  char* p = (char*)d_ws;
  float* e = (float*)p;            p += ACTL * 4;
  float* tb = (float*)p;           p += ACTL * 4;
  float* pe = (float*)p;           p += (long)SEQ * DM * 4;
  float* dd = (float*)p;           p += NB * DM * 4;
  float* da = (float*)p;           p += NB * DM * 4;
  float* dh = (float*)p;           p += NB * DFF * 4;
  float* df = (float*)p;           p += NB * DM * 4;
  p = (char*)(((uintptr_t)p + 255) & ~(uintptr_t)255);
  __bf16* eb = (__bf16*)p;         p += ACTL * 2;
  __bf16* qkvb = (__bf16*)p;       p += 3 * ACTL * 2;   // Q,K; slice 2 = V^T
  __bf16* hbb = (__bf16*)p;        p += (long)M * DFF * 2;
  __bf16* kvb = (__bf16*)p;        p += 12L * ACTL * 2; // [layer][K,V][4096][512]
  __bf16* wtq = (__bf16*)p;        p += 18L * WQS * 2;
  __bf16* wtf1 = (__bf16*)p;       p += 6L * WFS * 2;
  __bf16* wtf2 = (__bf16*)p;       p += 6L * WFS * 2;
  __bf16* wtd = (__bf16*)p;        p += 18L * WQS * 2;  // dec_qkv2^T
  __bf16* wtd1 = (__bf16*)p;       p += 18L * WQS * 2;  // dec_qkv1 V-slices^T (6 used)
  __bf16* wf1t = (__bf16*)p;       p += 6L * WFS * 2;
  __bf16* wf2t = (__bf16*)p;       p += 6L * WFS * 2;
  __bf16* wot = (__bf16*)p;        p += (long)OUTD * DM * 2;

  __bf16* vtb = qkvb + 2 * ACTL;
  float* tb2 = (float*)kvb;      // FFN2 split-K partial-1 (kvb idle until KV gemm)
  float* tbuf = dd;
  float* xbuf = pe;

  // ---- one-time prep (merged transposes: 5 dispatches total) ----
  pe_kernel<<<SEQ, 256, 0, stream>>>(pe);
  transpose_w3<<<dim3(16, 16, 42), 256, 0, stream>>>(
      enc_qkv_w, wtq, 18, dec_qkv2_w, wtd, 18, dec_qkv1_w, wtd1, 3, 2, DM, DM);
  transpose_w3<<<dim3(64, 16, 12), 256, 0, stream>>>(
      enc_ffn1_w, wtf1, 6, dec_ffn1_w, wf1t, 6, nullptr, nullptr, 0, 0, DM, DFF);
  transpose_w3<<<dim3(16, 64, 12), 256, 0, stream>>>(
      enc_ffn2_w, wtf2, 6, dec_ffn2_w, wf2t, 6, nullptr, nullptr, 0, 0, DFF, DM);
  transpose_ow<<<dim3(32, 16), 256, 0, stream>>>(out_w, wot);

  // ---- encoder ----
  embed_enc<<<(M * DM / 2) / 256, 256, 0, stream>>>(x, in_emb, pe, e, eb);
  for (int i = 0; i < NL; ++i) {
    mfma_gemm<64, 1, false, false, true, true, false><<<dim3(8, 32, 3), 256, 0, stream>>>(
        eb, wtq + (size_t)i * 3 * WQS, enc_qkv_b + (size_t)i * 3 * DM,
        nullptr, qkvb, vtb, M, DM, DM, WQS, DM, ACTL);
    attn_mfma<<<dim3(SEQ / 16, NB * NH), 256, 0, stream>>>(qkvb, vtb, tb);
    add_ln<true><<<M, 256, 0, stream>>>(tb, nullptr, e, nullptr,
                                        enc_ln1_g + i * DM, enc_ln1_b + i * DM,
                                        e, eb);
    mfma_gemm<64, 1, true, false, true, false, false><<<dim3(32, 32, 1), 256, 0, stream>>>(
        eb, wtf1 + (size_t)i * WFS, enc_ffn1_b + (size_t)i * DFF,
        nullptr, hbb, nullptr, M, DFF, DM, 0, 0, 0);
    mfma_gemm<64, 2, false, true, false, false, false><<<dim3(8, 32, 2), 256, 0, stream>>>(
        hbb, wtf2 + (size_t)i * WFS, enc_ffn2_b + (size_t)i * DM,
        tb, nullptr, nullptr, M, DM, DFF, 0, 0, (long)(tb2 - tb));
    add_ln<true><<<M, 256, 0, stream>>>(tb, tb2, e, nullptr,
                                        enc_ln2_g + i * DM, enc_ln2_b + i * DM,
                                        e, eb);
  }

  // ---- cross K/V for all 6 layers in one dispatch (bf16 out) ----
  mfma_gemm<64, 1, false, false, true, false, true><<<dim3(8, 32, 12), 256, 0, stream>>>(
      eb, wtd, dec_qkv2_b, nullptr, kvb, nullptr, M, DM, DM, WQS, DM, ACTL);

  // ---- decoder: 3 dispatches per layer ----
  for (int i = 0; i < NL; ++i) {
    const __bf16* Wv = wtd1 + (size_t)i * WQS;
    const float* bvp = dec_qkv1_b + ((size_t)i * 3 + 2) * DM;
    const __bf16* Wq = wtd + (size_t)i * 3 * WQS;
    const float* qbp = dec_qkv2_b + (size_t)i * 3 * DM;
    const __bf16* Kb = kvb + (size_t)i * 2 * ACTL;
    const __bf16* Vb = kvb + ((size_t)i * 2 + 1) * ACTL;
    if (i == 0)
      dec_attn<true><<<64, 256, 0, stream>>>(
          nullptr, nullptr, nullptr, nullptr, target, out_emb,
          Wv, bvp, dec_ln1_g + i * DM, dec_ln1_b + i * DM,
          Wq, qbp, Kb, Vb, da, tbuf);
    else
      dec_attn<false><<<64, 256, 0, stream>>>(
          df, xbuf, dec_ln3_g + (i - 1) * DM, dec_ln3_b + (i - 1) * DM,
          nullptr, nullptr,
          Wv, bvp, dec_ln1_g + i * DM, dec_ln1_b + i * DM,
          Wq, qbp, Kb, Vb, da, tbuf);
    dec_ffn1f<<<DFF / 4, 256, 0, stream>>>(
        da, tbuf, dec_ln2_g + i * DM, dec_ln2_b + i * DM,
        wf1t + (size_t)i * WFS, dec_ffn1_b + (size_t)i * DFF, dh, xbuf);
    dec_ffn2<<<DM / 2, 256, 0, stream>>>(
        dh, wf2t + (size_t)i * WFS, dec_ffn2_b + (size_t)i * DM, df);
  }

  // ---- output projection (LN3 + gemv + bias fused) ----
  dec_outf<<<OUTD / 4, 256, 0, stream>>>(df, xbuf, dec_ln3_g + 5 * DM,
                                         dec_ln3_b + 5 * DM, wot, out_b,
                                         (float*)d_out);
}

// Round 10
// 1100.241 us; speedup vs baseline: 1.4132x; 1.0495x over previous
//
#include <hip/hip_runtime.h>
#include <hip/hip_bf16.h>

#define DM 512
#define NH 8
#define DK 64
#define SEQ 512
#define NB 8
#define NL 6
#define DFF 2048
#define OUTD 1000
#define EMB_SCALE 22.627416997969522f
#define PE_C (-0.017988946039015984f)   // -ln(10000)/512

typedef __bf16 bf16x8 __attribute__((ext_vector_type(8)));
typedef __bf16 bf16x4 __attribute__((ext_vector_type(4)));
typedef float f32x4 __attribute__((ext_vector_type(4)));

__device__ __forceinline__ void load16_lds(const __bf16* g, __bf16* l) {
  __builtin_amdgcn_global_load_lds(
      (const __attribute__((address_space(1))) void*)g,
      (__attribute__((address_space(3))) void*)l, 16, 0, 0);
}

__device__ __forceinline__ float dot8(bf16x8 w, const float* a) {
  float s = 0.f;
#pragma unroll
  for (int j = 0; j < 8; ++j) s += (float)w[j] * a[j];
  return s;
}

// block-wide LN over a 512-elem row held as (v0 @ tid, v1 @ tid+256).
__device__ __forceinline__ void ln_pair(float v0, float v1, int tid,
                                        const float* __restrict__ g,
                                        const float* __restrict__ beta,
                                        float* out, float* ps, float* pq) {
  float s = v0 + v1, sq = v0 * v0 + v1 * v1;
  for (int o = 32; o > 0; o >>= 1) { s += __shfl_xor(s, o); sq += __shfl_xor(sq, o); }
  int wv = tid >> 6;
  if ((tid & 63) == 0) { ps[wv] = s; pq[wv] = sq; }
  __syncthreads();
  s = ps[0] + ps[1] + ps[2] + ps[3];
  sq = pq[0] + pq[1] + pq[2] + pq[3];
  float mean = s * (1.f / DM);
  float rstd = rsqrtf(sq * (1.f / DM) - mean * mean + 1e-5f);
  out[tid] = (v0 - mean) * rstd * g[tid] + beta[tid];
  out[tid + 256] = (v1 - mean) * rstd * g[tid + 256] + beta[tid + 256];
  __syncthreads();
}

// ---------------- PE table ----------------
__global__ __launch_bounds__(256) void pe_kernel(float* __restrict__ pe) {
  int s = blockIdx.x;
  int d2 = threadIdx.x;
  float div = expf((float)(2 * d2) * PE_C);
  float arg = (float)s * div;
  pe[(size_t)s * DM + 2 * d2] = sinf(arg);
  pe[(size_t)s * DM + 2 * d2 + 1] = cosf(arg);
}

// ---------------- embedding (float2 vectorized) ----------------
__global__ __launch_bounds__(256) void embed_enc(const int* __restrict__ x,
                                                 const float* __restrict__ emb,
                                                 const float* __restrict__ pe,
                                                 float* __restrict__ e,
                                                 __bf16* __restrict__ eb) {
  int idx = blockIdx.x * 256 + threadIdx.x;   // 2-elem granule index
  int d2 = idx & 255;
  int bs = idx >> 8;
  int s = bs & (SEQ - 1);
  int tok = x[bs];
  float2 ev = ((const float2*)(emb + (size_t)tok * DM))[d2];
  float2 pv = ((const float2*)(pe + (size_t)s * DM))[d2];
  float v0 = ev.x * EMB_SCALE + pv.x;
  float v1 = ev.y * EMB_SCALE + pv.y;
  ((float2*)e)[idx] = make_float2(v0, v1);
  union { __bf16 h[2]; unsigned u; } pk;
  pk.h[0] = (__bf16)v0; pk.h[1] = (__bf16)v1;
  ((unsigned*)eb)[idx] = pk.u;
}

// ---------------- merged weight transpose fp32[K][N] -> bf16[N][K] ---------
__global__ __launch_bounds__(256) void transpose_w3(
    const float* __restrict__ W0, __bf16* __restrict__ T0, int n0,
    const float* __restrict__ W1, __bf16* __restrict__ T1, int n1,
    const float* __restrict__ W2, __bf16* __restrict__ T2,
    long zmul2, long zadd2, int K, int N) {
  __shared__ float t[32][33];
  int z = blockIdx.z;
  const float* W;
  __bf16* WT;
  if (z < n0) {
    W = W0 + (size_t)z * K * N; WT = T0 + (size_t)z * K * N;
  } else if (z < n0 + n1) {
    int zz = z - n0;
    W = W1 + (size_t)zz * K * N; WT = T1 + (size_t)zz * K * N;
  } else {
    int zz = z - n0 - n1;
    W = W2 + (size_t)(zz * zmul2 + zadd2) * K * N;
    WT = T2 + (size_t)zz * K * N;
  }
  int k0 = blockIdx.y * 32, n0b = blockIdx.x * 32;
  int tx = threadIdx.x & 7, ty = threadIdx.x >> 3;
  float4 v = *(const float4*)&W[(size_t)(k0 + ty) * N + n0b + tx * 4];
  t[ty][tx * 4 + 0] = v.x; t[ty][tx * 4 + 1] = v.y;
  t[ty][tx * 4 + 2] = v.z; t[ty][tx * 4 + 3] = v.w;
  __syncthreads();
  bf16x4 o;
  o[0] = (__bf16)t[tx * 4 + 0][ty];
  o[1] = (__bf16)t[tx * 4 + 1][ty];
  o[2] = (__bf16)t[tx * 4 + 2][ty];
  o[3] = (__bf16)t[tx * 4 + 3][ty];
  *(bf16x4*)&WT[(size_t)(n0b + ty) * K + k0 + tx * 4] = o;
}

// out_w fp32 [512][1000] -> bf16 [1000][512] (guarded tail)
__global__ __launch_bounds__(256) void transpose_ow(const float* __restrict__ W,
                                                    __bf16* __restrict__ WT) {
  __shared__ float t[32][33];
  int n0 = blockIdx.x * 32, k0 = blockIdx.y * 32;
  int tid = threadIdx.x;
  for (int i = tid; i < 1024; i += 256) {
    int kk = i >> 5, nn = i & 31;
    t[kk][nn] = (n0 + nn < OUTD) ? W[(size_t)(k0 + kk) * OUTD + n0 + nn] : 0.f;
  }
  __syncthreads();
  for (int i = tid; i < 1024; i += 256) {
    int nn = i >> 5, kk = i & 31;
    if (n0 + nn < OUTD)
      WT[(size_t)(n0 + nn) * DM + k0 + kk] = (__bf16)t[kk][nn];
  }
}

// ---------------- MFMA GEMM (8 waves, BM=128 x BN=128): R2 structure -------
// Measured 42.4-43.0 us on the KV/QKV shapes vs 44.5-45.6 for the 4-wave
// BN=64 version (R2 vs R3 counters) — used for QKV/FFN1/KV dispatches.
template <int BN, bool RELU, bool WF32, bool WBF16, bool TRV, bool KVM>
__global__ __launch_bounds__(512) void mfma_gemm8(
    const __bf16* __restrict__ A, const __bf16* __restrict__ BT,
    const float* __restrict__ bias, float* __restrict__ C,
    __bf16* __restrict__ Cb, __bf16* __restrict__ Vt, int M, int N, int K,
    long btStride, long bStride, long cStride) {
  // XCD swizzle: each XCD owns a contiguous y-chunk; x fastest, z slowest.
  int gx = gridDim.x, gy = gridDim.y;
  int lin = blockIdx.x + gx * (blockIdx.y + gy * blockIdx.z);
  int xcd = lin & 7, li = lin >> 3;
  int yc = gy >> 3;
  int bx = li % gx;
  int t2 = li / gx;
  int by = xcd * yc + (t2 % yc);
  int z = t2 / yc;

  if (KVM) {
    long idx = (long)(z >> 1) * 3 + 1 + (z & 1);
    BT += idx * btStride;
    bias += idx * bStride;
  } else {
    BT += (size_t)z * btStride;
    bias += (size_t)z * bStride;
  }
  if (WF32) C += (size_t)z * cStride;
  if (WBF16) Cb += (size_t)z * cStride;

  constexpr int NI = BN / 32;
  __shared__ __bf16 As[2][128 * 64];
  __shared__ __bf16 Bs[2][BN * 64];

  int tid = threadIdx.x;
  int wave = tid >> 6, lane = tid & 63;
  int wm = wave >> 1, wn = wave & 1;           // 4 x 2 wave grid
  int quad = lane >> 4, l16 = lane & 15;
  int rlane = lane >> 3, c8 = lane & 7;
  int m0 = by * 128, n0 = bx * BN;
  int gcol = ((c8 ^ rlane) * 8);

  f32x4 acc[2][NI];
#pragma unroll
  for (int i = 0; i < 2; ++i)
#pragma unroll
    for (int j = 0; j < NI; ++j) acc[i][j] = (f32x4){0.f, 0.f, 0.f, 0.f};

  auto stage = [&](int buf, int k0) {
#pragma unroll
    for (int j = 0; j < 2; ++j) {
      int rb = j * 64 + wave * 8;
      load16_lds(&A[(size_t)(m0 + rb + rlane) * K + k0 + gcol],
                 &As[buf][rb * 64]);
    }
#pragma unroll
    for (int j = 0; j < BN / 64; ++j) {
      int rb = j * 64 + wave * 8;
      load16_lds(&BT[(size_t)(n0 + rb + rlane) * K + k0 + gcol],
                 &Bs[buf][rb * 64]);
    }
  };

  const int NT = K >> 6;
  stage(0, 0);
  __syncthreads();
  for (int t = 0; t < NT; ++t) {
    int cur = t & 1;
    if (t + 1 < NT) stage(cur ^ 1, (t + 1) << 6);
#pragma unroll
    for (int kk = 0; kk < 64; kk += 32) {
      bf16x8 af[2], bfr[NI];
#pragma unroll
      for (int i = 0; i < 2; ++i) {
        int row = wm * 32 + i * 16 + l16;
        af[i] = *(const bf16x8*)&As[cur][row * 64 + ((((kk >> 3) + quad) ^ (row & 7)) * 8)];
      }
#pragma unroll
      for (int i = 0; i < NI; ++i) {
        int row = wn * (BN / 2) + i * 16 + l16;
        bfr[i] = *(const bf16x8*)&Bs[cur][row * 64 + ((((kk >> 3) + quad) ^ (row & 7)) * 8)];
      }
#pragma unroll
      for (int mi = 0; mi < 2; ++mi)
#pragma unroll
        for (int ni = 0; ni < NI; ++ni)
          acc[mi][ni] = __builtin_amdgcn_mfma_f32_16x16x32_bf16(
              af[mi], bfr[ni], acc[mi][ni], 0, 0, 0);
    }
    __syncthreads();
  }

#pragma unroll
  for (int ni = 0; ni < NI; ++ni) {
    int col = n0 + wn * (BN / 2) + ni * 16 + l16;
    float bv = bias[col];
    if (TRV && z == 2) {
      int b = m0 >> 9;
#pragma unroll
      for (int mi = 0; mi < 2; ++mi) {
        int srow = (m0 & 511) + wm * 32 + mi * 16 + quad * 4;
        bf16x4 pk;
#pragma unroll
        for (int r = 0; r < 4; ++r) pk[r] = (__bf16)(acc[mi][ni][r] + bv);
        *(bf16x4*)&Vt[((size_t)(b * 512 + col)) * 512 + srow] = pk;
      }
    } else {
#pragma unroll
      for (int mi = 0; mi < 2; ++mi) {
#pragma unroll
        for (int r = 0; r < 4; ++r) {
          int row = m0 + wm * 32 + mi * 16 + quad * 4 + r;
          float v = acc[mi][ni][r] + bv;
          if (RELU) v = fmaxf(v, 0.f);
          if (WF32) C[(size_t)row * N + col] = v;
          if (WBF16) Cb[(size_t)row * N + col] = (__bf16)v;
        }
      }
    }
  }
}

// ---------------- MFMA GEMM (4 waves, BM=128 x BN=64, split-K): R3 ---------
// Used for FFN2 (N=512, K=2048) where split-K=2 doubles grid fill.
template <int BN, int SK, bool RELU, bool WF32, bool WBF16>
__global__ __launch_bounds__(256) void mfma_gemm(
    const __bf16* __restrict__ A, const __bf16* __restrict__ BT,
    const float* __restrict__ bias, float* __restrict__ C,
    __bf16* __restrict__ Cb, int M, int N, int K, long cStride) {
  int gx = gridDim.x, gy = gridDim.y;
  int lin = blockIdx.x + gx * (blockIdx.y + gy * blockIdx.z);
  int xcd = lin & 7, li = lin >> 3;
  int yc = gy >> 3;
  int bx = li % gx;
  int t2 = li / gx;
  int by = xcd * yc + (t2 % yc);
  int z = t2 / yc;

  if (WF32) C += (size_t)z * cStride;
  if (WBF16) Cb += (size_t)z * cStride;

  constexpr int NI = BN / 32;
  __shared__ __bf16 As[2][128 * 64];
  __shared__ __bf16 Bs[2][BN * 64];

  int tid = threadIdx.x;
  int wave = tid >> 6, lane = tid & 63;
  int wm = wave >> 1, wn = wave & 1;           // 2 x 2 wave grid
  int quad = lane >> 4, l16 = lane & 15;
  int rlane = lane >> 3, c8 = lane & 7;
  int m0 = by * 128, n0 = bx * BN;
  int gcol = ((c8 ^ rlane) * 8);

  f32x4 acc[4][NI];
#pragma unroll
  for (int i = 0; i < 4; ++i)
#pragma unroll
    for (int j = 0; j < NI; ++j) acc[i][j] = (f32x4){0.f, 0.f, 0.f, 0.f};

  auto stage = [&](int buf, int k0) {
#pragma unroll
    for (int j = 0; j < 4; ++j) {
      int rb = j * 32 + wave * 8;
      load16_lds(&A[(size_t)(m0 + rb + rlane) * K + k0 + gcol],
                 &As[buf][rb * 64]);
    }
#pragma unroll
    for (int j = 0; j < BN / 32; ++j) {
      int rb = j * 32 + wave * 8;
      load16_lds(&BT[(size_t)(n0 + rb + rlane) * K + k0 + gcol],
                 &Bs[buf][rb * 64]);
    }
  };

  int kLen = (SK > 1) ? (K / SK) : K;
  int kBeg = (SK > 1) ? z * kLen : 0;
  const int NT = kLen >> 6;
  stage(0, kBeg);
  __syncthreads();
  for (int t = 0; t < NT; ++t) {
    int cur = t & 1;
    if (t + 1 < NT) stage(cur ^ 1, kBeg + ((t + 1) << 6));
#pragma unroll
    for (int kk = 0; kk < 64; kk += 32) {
      bf16x8 af[4], bfr[NI];
#pragma unroll
      for (int i = 0; i < 4; ++i) {
        int row = wm * 64 + i * 16 + l16;
        af[i] = *(const bf16x8*)&As[cur][row * 64 + ((((kk >> 3) + quad) ^ (row & 7)) * 8)];
      }
#pragma unroll
      for (int i = 0; i < NI; ++i) {
        int row = wn * (BN / 2) + i * 16 + l16;
        bfr[i] = *(const bf16x8*)&Bs[cur][row * 64 + ((((kk >> 3) + quad) ^ (row & 7)) * 8)];
      }
#pragma unroll
      for (int mi = 0; mi < 4; ++mi)
#pragma unroll
        for (int ni = 0; ni < NI; ++ni)
          acc[mi][ni] = __builtin_amdgcn_mfma_f32_16x16x32_bf16(
              af[mi], bfr[ni], acc[mi][ni], 0, 0, 0);
    }
    __syncthreads();
  }

#pragma unroll
  for (int ni = 0; ni < NI; ++ni) {
    int col = n0 + wn * (BN / 2) + ni * 16 + l16;
    float bv = (SK == 1 || z == 0) ? bias[col] : 0.f;
#pragma unroll
    for (int mi = 0; mi < 4; ++mi) {
#pragma unroll
      for (int r = 0; r < 4; ++r) {
        int row = m0 + wm * 64 + mi * 16 + quad * 4 + r;
        float v = acc[mi][ni][r] + bv;
        if (RELU) v = fmaxf(v, 0.f);
        if (WF32) C[(size_t)row * N + col] = v;
        if (WBF16) Cb[(size_t)row * N + col] = (__bf16)v;
      }
    }
  }
}

// ---------------- MFMA encoder attention (staged, dbuf prefetch-1) ---------
// R7/R3 structure — confirmed best (R5 widening null, R9 zero-staging -40us).
#define SCP 520
__global__ __launch_bounds__(256) void attn_mfma(const __bf16* __restrict__ QKV,
                                                 const __bf16* __restrict__ Vt,
                                                 float* __restrict__ O) {
  __shared__ __bf16 Sc[16 * SCP];
  __shared__ __bf16 Tt[2][64 * 64];

  const long ACTL = (long)NB * SEQ * DM;
  int tid = threadIdx.x;
  int wave = tid >> 6, lane = tid & 63;
  int quad = lane >> 4, l16 = lane & 15;
  int rlane = lane >> 3, c8 = lane & 7;
  // XCD swizzle: chunk by bh so each XCD's L2 holds few K/V panels.
  int lin = blockIdx.x + gridDim.x * blockIdx.y;
  int xcd = lin & 7, li = lin >> 3;
  int yc = gridDim.y >> 3;
  int q0 = (li % gridDim.x) * 16;
  int bh = xcd * yc + li / gridDim.x;
  int b = bh >> 3, h = bh & 7;
  const __bf16* Q = QKV;
  const __bf16* Kp = QKV + ACTL;
  size_t baseQ = ((size_t)b * SEQ + q0) * DM + h * DK;
  size_t baseK = ((size_t)b * SEQ) * DM + h * DK;
  const __bf16* VtB = Vt + ((size_t)(b * 512 + h * 64)) * 512;
  int gcol = (c8 ^ rlane) * 8;

  bf16x8 af0 = *(const bf16x8*)&Q[baseQ + (size_t)l16 * DM + quad * 8];
  bf16x8 af1 = *(const bf16x8*)&Q[baseQ + (size_t)l16 * DM + 32 + quad * 8];

  auto stageK = [&](int buf, int kt) {
#pragma unroll
    for (int j = 0; j < 2; ++j) {
      int row = j * 32 + wave * 8 + rlane;
      load16_lds(&Kp[baseK + (size_t)(kt * 64 + row) * DM + gcol],
                 &Tt[buf][(j * 32 + wave * 8) * 64]);
    }
  };
  auto stageV = [&](int buf, int kt) {
#pragma unroll
    for (int j = 0; j < 2; ++j) {
      int row = j * 32 + wave * 8 + rlane;
      load16_lds(&VtB[(size_t)row * 512 + kt * 64 + gcol],
                 &Tt[buf][(j * 32 + wave * 8) * 64]);
    }
  };

  // ---- QK^T, 8 tiles, prefetch-1 ----
  stageK(0, 0);
  __syncthreads();
  for (int kt = 0; kt < 8; ++kt) {
    int cur = kt & 1;
    if (kt < 7) stageK(cur ^ 1, kt + 1);
    f32x4 acc = (f32x4){0.f, 0.f, 0.f, 0.f};
    int krow = wave * 16 + l16, sw = krow & 7;
    bf16x8 b0 = *(const bf16x8*)&Tt[cur][krow * 64 + ((quad ^ sw) * 8)];
    bf16x8 b1 = *(const bf16x8*)&Tt[cur][krow * 64 + (((4 + quad) ^ sw) * 8)];
    acc = __builtin_amdgcn_mfma_f32_16x16x32_bf16(af0, b0, acc, 0, 0, 0);
    acc = __builtin_amdgcn_mfma_f32_16x16x32_bf16(af1, b1, acc, 0, 0, 0);
#pragma unroll
    for (int r = 0; r < 4; ++r)
      Sc[(quad * 4 + r) * SCP + kt * 64 + wave * 16 + l16] =
          (__bf16)(acc[r] * 0.125f);
    __syncthreads();
  }

  // prefetch first V tile under softmax
  stageV(0, 0);

  // ---- softmax over 16 rows ----
#pragma unroll
  for (int rr = 0; rr < 4; ++rr) {
    int r = wave * 4 + rr;
    float v[8];
    float mx = -1e30f;
#pragma unroll
    for (int j = 0; j < 8; ++j) {
      v[j] = (float)Sc[r * SCP + j * 64 + lane];
      mx = fmaxf(mx, v[j]);
    }
    for (int o = 32; o > 0; o >>= 1) mx = fmaxf(mx, __shfl_xor(mx, o));
    float sum = 0.f;
#pragma unroll
    for (int j = 0; j < 8; ++j) { v[j] = __expf(v[j] - mx); sum += v[j]; }
    for (int o = 32; o > 0; o >>= 1) sum += __shfl_xor(sum, o);
    float inv = 1.f / sum;
#pragma unroll
    for (int j = 0; j < 8; ++j)
      Sc[r * SCP + j * 64 + lane] = (__bf16)(v[j] * inv);
  }
  __syncthreads();  // softmax Sc visible + V tile 0 staged (vmcnt drain)

  // ---- PV, 8 tiles, prefetch-1 ----
  f32x4 oacc = (f32x4){0.f, 0.f, 0.f, 0.f};
  for (int kt = 0; kt < 8; ++kt) {
    int cur = kt & 1;
    if (kt < 7) stageV(cur ^ 1, kt + 1);
    int drow = wave * 16 + l16, sw = drow & 7;
#pragma unroll
    for (int kk = 0; kk < 64; kk += 32) {
      bf16x8 pa = *(const bf16x8*)&Sc[l16 * SCP + kt * 64 + kk + quad * 8];
      bf16x8 vb = *(const bf16x8*)&Tt[cur][drow * 64 + ((((kk >> 3) + quad) ^ sw) * 8)];
      oacc = __builtin_amdgcn_mfma_f32_16x16x32_bf16(pa, vb, oacc, 0, 0, 0);
    }
    __syncthreads();
  }
#pragma unroll
  for (int r = 0; r < 4; ++r)
    O[((size_t)b * SEQ + q0 + quad * 4 + r) * DM + h * DK + wave * 16 + l16] =
        oacc[r];
}

// ---------------- residual + layernorm (float2 vectorized) -------
template <bool WB>
__global__ __launch_bounds__(256) void add_ln(
    const float* __restrict__ x, const float* __restrict__ x2,
    const float* __restrict__ res, const float* __restrict__ cbias,
    const float* __restrict__ g, const float* __restrict__ beta,
    float* __restrict__ y, __bf16* __restrict__ yb) {
  int row = blockIdx.x;
  int tid = threadIdx.x;                // one float2 (cols 2t,2t+1) per thread
  float2 xv = ((const float2*)(x + (size_t)row * DM))[tid];
  float2 rv = ((const float2*)(res + (size_t)row * DM))[tid];
  float v0 = xv.x + rv.x;
  float v1 = xv.y + rv.y;
  if (cbias) {
    float2 cb = ((const float2*)cbias)[tid];
    v0 += cb.x; v1 += cb.y;
  }
  if (x2) {
    float2 x2v = ((const float2*)(x2 + (size_t)row * DM))[tid];
    v0 += x2v.x; v1 += x2v.y;
  }
  float s = v0 + v1, sq = v0 * v0 + v1 * v1;
  for (int o = 32; o > 0; o >>= 1) {
    s += __shfl_xor(s, o);
    sq += __shfl_xor(sq, o);
  }
  __shared__ float ps[4], pq[4];
  int wv = tid >> 6;
  if ((tid & 63) == 0) { ps[wv] = s; pq[wv] = sq; }
  __syncthreads();
  s = ps[0] + ps[1] + ps[2] + ps[3];
  sq = pq[0] + pq[1] + pq[2] + pq[3];
  float mean = s * (1.f / DM);
  float var = sq * (1.f / DM) - mean * mean;
  float rstd = rsqrtf(var + 1e-5f);
  float2 gg = ((const float2*)g)[tid];
  float2 bb = ((const float2*)beta)[tid];
  float o0 = (v0 - mean) * rstd * gg.x + bb.x;
  float o1 = (v1 - mean) * rstd * gg.y + bb.y;
  ((float2*)(y + (size_t)row * DM))[tid] = make_float2(o0, o1);
  if (WB) {
    union { __bf16 h[2]; unsigned u; } pk;
    pk.h[0] = (__bf16)o0; pk.h[1] = (__bf16)o1;
    ((unsigned*)(yb + (size_t)row * DM))[tid] = pk.u;
  }
}

// ============ fused decoder (3 dispatches/layer) ============

// one block per (b,h); LN1/LN3 recomputed redundantly per block (cheap)
template <bool FIRST>
__global__ __launch_bounds__(256) void dec_attn(
    const float* __restrict__ dfp, const float* __restrict__ xp,
    const float* __restrict__ g3, const float* __restrict__ b3,
    const int* __restrict__ target, const float* __restrict__ emb,
    const __bf16* __restrict__ WvT, const float* __restrict__ bv,
    const float* __restrict__ g1, const float* __restrict__ b1ln,
    const __bf16* __restrict__ WqT, const float* __restrict__ qb,
    const __bf16* __restrict__ Kb, const __bf16* __restrict__ Vb,
    float* __restrict__ da, float* __restrict__ tbuf) {
  __shared__ float arow[DM];
  __shared__ float trow[DM];
  __shared__ float red[4][64];
  __shared__ float q[64];
  __shared__ float sc[SEQ];
  __shared__ float wred[4];
  __shared__ float ps[4], pq[4];

  int bh = blockIdx.x, b = bh >> 3, h = bh & 7;
  int tid = threadIdx.x, lane = tid & 63, wave = tid >> 6;

  // ---- dd (layer input) ----
  if (FIRST) {
    int tok = target[b];
    arow[tid] = emb[(size_t)tok * DM + tid] * EMB_SCALE + ((tid & 1) ? 1.f : 0.f);
    arow[tid + 256] =
        emb[(size_t)tok * DM + tid + 256] * EMB_SCALE + ((tid & 1) ? 1.f : 0.f);
    __syncthreads();
  } else {
    float v0 = dfp[(size_t)b * DM + tid] + xp[(size_t)b * DM + tid];
    float v1 = dfp[(size_t)b * DM + tid + 256] + xp[(size_t)b * DM + tid + 256];
    ln_pair(v0, v1, tid, g3, b3, arow, ps, pq);
  }

  // ---- t = LN1(dd + dd@Wv + bv) ----
  float o0, o1;
  {
    const __bf16* w = &WvT[(size_t)tid * DM];
    float acc = 0.f;
#pragma unroll 4
    for (int k = 0; k < DM; k += 8) acc += dot8(*(const bf16x8*)&w[k], &arow[k]);
    o0 = arow[tid] + acc + bv[tid];
  }
  {
    const __bf16* w = &WvT[(size_t)(tid + 256) * DM];
    float acc = 0.f;
#pragma unroll 4
    for (int k = 0; k < DM; k += 8) acc += dot8(*(const bf16x8*)&w[k], &arow[k]);
    o1 = arow[tid + 256] + acc + bv[tid + 256];
  }
  ln_pair(o0, o1, tid, g1, b1ln, trow, ps, pq);
  if (h == 0) {
    tbuf[(size_t)b * DM + tid] = trow[tid];
    tbuf[(size_t)b * DM + tid + 256] = trow[tid + 256];
  }

  // ---- q-gemv: 64 cols x 4 k-subs from trow ----
  {
    int c = tid & 63, s = tid >> 6;
    const __bf16* w = &WqT[(size_t)(h * 64 + c) * DM + s * 128];
    float acc = 0.f;
#pragma unroll
    for (int k = 0; k < 128; k += 8)
      acc += dot8(*(const bf16x8*)&w[k], &trow[s * 128 + k]);
    red[s][c] = acc;
  }
  __syncthreads();
  if (tid < 64)
    q[tid] = red[0][tid] + red[1][tid] + red[2][tid] + red[3][tid] + qb[h * 64 + tid];
  __syncthreads();

  // ---- scores ----
  for (int key = tid; key < SEQ; key += 256) {
    const __bf16* kp = &Kb[((size_t)b * SEQ + key) * DM + h * 64];
    float acc = 0.f;
#pragma unroll
    for (int k = 0; k < 64; k += 8) acc += dot8(*(const bf16x8*)&kp[k], &q[k]);
    sc[key] = acc * 0.125f;
  }
  __syncthreads();
  float m = -1e30f;
  for (int j = tid; j < SEQ; j += 256) m = fmaxf(m, sc[j]);
  for (int o = 32; o > 0; o >>= 1) m = fmaxf(m, __shfl_xor(m, o));
  if (lane == 0) wred[wave] = m;
  __syncthreads();
  m = fmaxf(fmaxf(wred[0], wred[1]), fmaxf(wred[2], wred[3]));
  float sum = 0.f;
  for (int j = tid; j < SEQ; j += 256) {
    float p = __expf(sc[j] - m);
    sc[j] = p;
    sum += p;
  }
  for (int o = 32; o > 0; o >>= 1) sum += __shfl_xor(sum, o);
  __syncthreads();
  if (lane == 0) wred[wave] = sum;
  __syncthreads();
  float inv = 1.f / (wred[0] + wred[1] + wred[2] + wred[3]);

  // ---- PV ----
  {
    int d = tid & 63, s = tid >> 6;
    float acc = 0.f;
    const __bf16* vp = &Vb[((size_t)b * SEQ + s * 128) * DM + h * 64 + d];
#pragma unroll 8
    for (int k = 0; k < 128; ++k) acc += sc[s * 128 + k] * (float)vp[(size_t)k * DM];
    red[s][d] = acc;
  }
  __syncthreads();
  if (tid < 64)
    da[(size_t)b * DM + h * 64 + tid] =
        (red[0][tid] + red[1][tid] + red[2][tid] + red[3][tid]) * inv;
}

// x2 = LN2(da + t) recomputed per block; h = relu(x2@W1+b1); blk0 saves x2
__global__ __launch_bounds__(256) void dec_ffn1f(
    const float* __restrict__ da, const float* __restrict__ tbuf,
    const float* __restrict__ g2, const float* __restrict__ b2ln,
    const __bf16* __restrict__ W1T, const float* __restrict__ b1,
    float* __restrict__ h, float* __restrict__ xbuf) {
  __shared__ float a[8][DM];
  __shared__ float ps[4], pq[4];
  int tid = threadIdx.x, lane = tid & 63, wave = tid >> 6;
  for (int r = 0; r < 8; ++r) {
    float v0 = da[(size_t)r * DM + tid] + tbuf[(size_t)r * DM + tid];
    float v1 = da[(size_t)r * DM + tid + 256] + tbuf[(size_t)r * DM + tid + 256];
    ln_pair(v0, v1, tid, g2, b2ln, a[r], ps, pq);
  }
  int col = blockIdx.x * 4 + wave;
  bf16x8 w = *(const bf16x8*)&W1T[(size_t)col * DM + lane * 8];
  float acc[8];
#pragma unroll
  for (int r = 0; r < 8; ++r) acc[r] = dot8(w, &a[r][lane * 8]);
#pragma unroll
  for (int r = 0; r < 8; ++r)
    for (int o = 32; o > 0; o >>= 1) acc[r] += __shfl_xor(acc[r], o);
  if (lane == 0) {
    float bb = b1[col];
#pragma unroll
    for (int r = 0; r < 8; ++r) h[(size_t)r * DFF + col] = fmaxf(acc[r] + bb, 0.f);
  }
  if (blockIdx.x == 0) {
#pragma unroll
    for (int r = 0; r < 8; ++r) {
      xbuf[(size_t)r * DM + tid] = a[r][tid];
      xbuf[(size_t)r * DM + tid + 256] = a[r][tid + 256];
    }
  }
}

// df[r][col] = h[r] @ W2T[col] + b2[col]; 2 cols/block, 2 waves per col
__global__ __launch_bounds__(256) void dec_ffn2(
    const float* __restrict__ h, const __bf16* __restrict__ W2T,
    const float* __restrict__ b2, float* __restrict__ df) {
  __shared__ float red[4][8];
  int tid = threadIdx.x, lane = tid & 63, wave = tid >> 6;
  int c = wave >> 1, half = wave & 1;
  int col = blockIdx.x * 2 + c;
  int k0 = half * 1024 + lane * 8;
  bf16x8 w0 = *(const bf16x8*)&W2T[(size_t)col * DFF + k0];
  bf16x8 w1 = *(const bf16x8*)&W2T[(size_t)col * DFF + k0 + 512];
  float acc[8];
#pragma unroll
  for (int r = 0; r < 8; ++r) {
    float4 h0a = *(const float4*)&h[(size_t)r * DFF + k0];
    float4 h0b = *(const float4*)&h[(size_t)r * DFF + k0 + 4];
    float4 h1a = *(const float4*)&h[(size_t)r * DFF + k0 + 512];
    float4 h1b = *(const float4*)&h[(size_t)r * DFF + k0 + 516];
    float hh0[8] = {h0a.x, h0a.y, h0a.z, h0a.w, h0b.x, h0b.y, h0b.z, h0b.w};
    float hh1[8] = {h1a.x, h1a.y, h1a.z, h1a.w, h1b.x, h1b.y, h1b.z, h1b.w};
    acc[r] = dot8(w0, hh0) + dot8(w1, hh1);
  }
#pragma unroll
  for (int r = 0; r < 8; ++r)
    for (int o = 32; o > 0; o >>= 1) acc[r] += __shfl_xor(acc[r], o);
  if (lane == 0) {
#pragma unroll
    for (int r = 0; r < 8; ++r) red[wave][r] = acc[r];
  }
  __syncthreads();
  if (tid < 16) {
    int cc = tid >> 3, r = tid & 7;
    int ocol = blockIdx.x * 2 + cc;
    df[(size_t)r * DM + ocol] =
        red[cc * 2][r] + red[cc * 2 + 1][r] + b2[ocol];
  }
}

// out = LN3_5(df + x2) @ Wo + ob  (LN recomputed per block)
__global__ __launch_bounds__(256) void dec_outf(
    const float* __restrict__ df, const float* __restrict__ xbuf,
    const float* __restrict__ g3, const float* __restrict__ b3,
    const __bf16* __restrict__ WoT, const float* __restrict__ ob,
    float* __restrict__ out) {
  __shared__ float a[8][DM];
  __shared__ float ps[4], pq[4];
  int tid = threadIdx.x, lane = tid & 63, wave = tid >> 6;
  for (int r = 0; r < 8; ++r) {
    float v0 = df[(size_t)r * DM + tid] + xbuf[(size_t)r * DM + tid];
    float v1 = df[(size_t)r * DM + tid + 256] + xbuf[(size_t)r * DM + tid + 256];
    ln_pair(v0, v1, tid, g3, b3, a[r], ps, pq);
  }
  int col = blockIdx.x * 4 + wave;
  bf16x8 w = *(const bf16x8*)&WoT[(size_t)col * DM + lane * 8];
  float acc[8];
#pragma unroll
  for (int r = 0; r < 8; ++r) acc[r] = dot8(w, &a[r][lane * 8]);
#pragma unroll
  for (int r = 0; r < 8; ++r)
    for (int o = 32; o > 0; o >>= 1) acc[r] += __shfl_xor(acc[r], o);
  if (lane == 0) {
    float bb = ob[col];
#pragma unroll
    for (int r = 0; r < 8; ++r) out[(size_t)r * OUTD + col] = acc[r] + bb;
  }
}

// ---------------------------------------------------------------------------
extern "C" void kernel_launch(void* const* d_in, const int* in_sizes, int n_in,
                              void* d_out, int out_size, void* d_ws, size_t ws_size,
                              hipStream_t stream) {
  const int* x = (const int*)d_in[0];
  const int* target = (const int*)d_in[1];
  const float* in_emb = (const float*)d_in[2];
  const float* out_emb = (const float*)d_in[3];
  const float* enc_qkv_w = (const float*)d_in[4];
  const float* enc_qkv_b = (const float*)d_in[5];
  const float* enc_ln1_g = (const float*)d_in[6];
  const float* enc_ln1_b = (const float*)d_in[7];
  const float* enc_ffn1_w = (const float*)d_in[8];
  const float* enc_ffn1_b = (const float*)d_in[9];
  const float* enc_ffn2_w = (const float*)d_in[10];
  const float* enc_ffn2_b = (const float*)d_in[11];
  const float* enc_ln2_g = (const float*)d_in[12];
  const float* enc_ln2_b = (const float*)d_in[13];
  const float* dec_qkv1_w = (const float*)d_in[14];
  const float* dec_qkv1_b = (const float*)d_in[15];
  const float* dec_ln1_g = (const float*)d_in[16];
  const float* dec_ln1_b = (const float*)d_in[17];
  const float* dec_qkv2_w = (const float*)d_in[18];
  const float* dec_qkv2_b = (const float*)d_in[19];
  const float* dec_ln2_g = (const float*)d_in[20];
  const float* dec_ln2_b = (const float*)d_in[21];
  const float* dec_ffn1_w = (const float*)d_in[22];
  const float* dec_ffn1_b = (const float*)d_in[23];
  const float* dec_ffn2_w = (const float*)d_in[24];
  const float* dec_ffn2_b = (const float*)d_in[25];
  const float* dec_ln3_g = (const float*)d_in[26];
  const float* dec_ln3_b = (const float*)d_in[27];
  const float* out_w = (const float*)d_in[28];
  const float* out_b = (const float*)d_in[29];

  const long ACTL = (long)NB * SEQ * DM;           // 2M elems
  const int M = NB * SEQ;                           // 4096
  const long WQS = (long)DM * DM;
  const long WFS = (long)DM * DFF;

  char* p = (char*)d_ws;
  float* e = (float*)p;            p += ACTL * 4;
  float* tb = (float*)p;           p += ACTL * 4;
  float* pe = (float*)p;           p += (long)SEQ * DM * 4;
  float* dd = (float*)p;           p += NB * DM * 4;
  float* da = (float*)p;           p += NB * DM * 4;
  float* dh = (float*)p;           p += NB * DFF * 4;
  float* df = (float*)p;           p += NB * DM * 4;
  p = (char*)(((uintptr_t)p + 255) & ~(uintptr_t)255);
  __bf16* eb = (__bf16*)p;         p += ACTL * 2;
  __bf16* qkvb = (__bf16*)p;       p += 3 * ACTL * 2;   // Q,K; slice 2 = V^T
  __bf16* hbb = (__bf16*)p;        p += (long)M * DFF * 2;
  __bf16* kvb = (__bf16*)p;        p += 12L * ACTL * 2; // [layer][K,V][4096][512]
  __bf16* wtq = (__bf16*)p;        p += 18L * WQS * 2;
  __bf16* wtf1 = (__bf16*)p;       p += 6L * WFS * 2;
  __bf16* wtf2 = (__bf16*)p;       p += 6L * WFS * 2;
  __bf16* wtd = (__bf16*)p;        p += 18L * WQS * 2;  // dec_qkv2^T
  __bf16* wtd1 = (__bf16*)p;       p += 18L * WQS * 2;  // dec_qkv1 V-slices^T (6 used)
  __bf16* wf1t = (__bf16*)p;       p += 6L * WFS * 2;
  __bf16* wf2t = (__bf16*)p;       p += 6L * WFS * 2;
  __bf16* wot = (__bf16*)p;        p += (long)OUTD * DM * 2;

  __bf16* vtb = qkvb + 2 * ACTL;
  float* tb2 = (float*)kvb;      // FFN2 split-K partial-1 (kvb idle until KV gemm)
  float* tbuf = dd;
  float* xbuf = pe;

  // ---- one-time prep (merged transposes: 5 dispatches total) ----
  pe_kernel<<<SEQ, 256, 0, stream>>>(pe);
  transpose_w3<<<dim3(16, 16, 42), 256, 0, stream>>>(
      enc_qkv_w, wtq, 18, dec_qkv2_w, wtd, 18, dec_qkv1_w, wtd1, 3, 2, DM, DM);
  transpose_w3<<<dim3(64, 16, 12), 256, 0, stream>>>(
      enc_ffn1_w, wtf1, 6, dec_ffn1_w, wf1t, 6, nullptr, nullptr, 0, 0, DM, DFF);
  transpose_w3<<<dim3(16, 64, 12), 256, 0, stream>>>(
      enc_ffn2_w, wtf2, 6, dec_ffn2_w, wf2t, 6, nullptr, nullptr, 0, 0, DFF, DM);
  transpose_ow<<<dim3(32, 16), 256, 0, stream>>>(out_w, wot);

  // ---- encoder ----
  embed_enc<<<(M * DM / 2) / 256, 256, 0, stream>>>(x, in_emb, pe, e, eb);
  for (int i = 0; i < NL; ++i) {
    mfma_gemm8<128, false, false, true, true, false><<<dim3(4, 32, 3), 512, 0, stream>>>(
        eb, wtq + (size_t)i * 3 * WQS, enc_qkv_b + (size_t)i * 3 * DM,
        nullptr, qkvb, vtb, M, DM, DM, WQS, DM, ACTL);
    attn_mfma<<<dim3(SEQ / 16, NB * NH), 256, 0, stream>>>(qkvb, vtb, tb);
    add_ln<true><<<M, 256, 0, stream>>>(tb, nullptr, e, nullptr,
                                        enc_ln1_g + i * DM, enc_ln1_b + i * DM,
                                        e, eb);
    mfma_gemm8<128, true, false, true, false, false><<<dim3(16, 32, 1), 512, 0, stream>>>(
        eb, wtf1 + (size_t)i * WFS, enc_ffn1_b + (size_t)i * DFF,
        nullptr, hbb, nullptr, M, DFF, DM, 0, 0, 0);
    mfma_gemm<64, 2, false, true, false><<<dim3(8, 32, 2), 256, 0, stream>>>(
        hbb, wtf2 + (size_t)i * WFS, enc_ffn2_b + (size_t)i * DM,
        tb, nullptr, M, DM, DFF, (long)(tb2 - tb));
    add_ln<true><<<M, 256, 0, stream>>>(tb, tb2, e, nullptr,
                                        enc_ln2_g + i * DM, enc_ln2_b + i * DM,
                                        e, eb);
  }

  // ---- cross K/V for all 6 layers in one dispatch (bf16 out) ----
  mfma_gemm8<128, false, false, true, false, true><<<dim3(4, 32, 12), 512, 0, stream>>>(
      eb, wtd, dec_qkv2_b, nullptr, kvb, nullptr, M, DM, DM, WQS, DM, ACTL);

  // ---- decoder: 3 dispatches per layer ----
  for (int i = 0; i < NL; ++i) {
    const __bf16* Wv = wtd1 + (size_t)i * WQS;
    const float* bvp = dec_qkv1_b + ((size_t)i * 3 + 2) * DM;
    const __bf16* Wq = wtd + (size_t)i * 3 * WQS;
    const float* qbp = dec_qkv2_b + (size_t)i * 3 * DM;
    const __bf16* Kb = kvb + (size_t)i * 2 * ACTL;
    const __bf16* Vb = kvb + ((size_t)i * 2 + 1) * ACTL;
    if (i == 0)
      dec_attn<true><<<64, 256, 0, stream>>>(
          nullptr, nullptr, nullptr, nullptr, target, out_emb,
          Wv, bvp, dec_ln1_g + i * DM, dec_ln1_b + i * DM,
          Wq, qbp, Kb, Vb, da, tbuf);
    else
      dec_attn<false><<<64, 256, 0, stream>>>(
          df, xbuf, dec_ln3_g + (i - 1) * DM, dec_ln3_b + (i - 1) * DM,
          nullptr, nullptr,
          Wv, bvp, dec_ln1_g + i * DM, dec_ln1_b + i * DM,
          Wq, qbp, Kb, Vb, da, tbuf);
    dec_ffn1f<<<DFF / 4, 256, 0, stream>>>(
        da, tbuf, dec_ln2_g + i * DM, dec_ln2_b + i * DM,
        wf1t + (size_t)i * WFS, dec_ffn1_b + (size_t)i * DFF, dh, xbuf);
    dec_ffn2<<<DM / 2, 256, 0, stream>>>(
        dh, wf2t + (size_t)i * WFS, dec_ffn2_b + (size_t)i * DM, df);
  }

  // ---- output projection (LN3 + gemv + bias fused) ----
  dec_outf<<<OUTD / 4, 256, 0, stream>>>(df, xbuf, dec_ln3_g + 5 * DM,
                                         dec_ln3_b + 5 * DM, wot, out_b,
                                         (float*)d_out);
}

// Round 11
// 1079.672 us; speedup vs baseline: 1.4401x; 1.0191x over previous
//
#include <hip/hip_runtime.h>
#include <hip/hip_bf16.h>

#define DM 512
#define NH 8
#define DK 64
#define SEQ 512
#define NB 8
#define NL 6
#define DFF 2048
#define OUTD 1000
#define EMB_SCALE 22.627416997969522f
#define PE_C (-0.017988946039015984f)   // -ln(10000)/512

typedef __bf16 bf16x8 __attribute__((ext_vector_type(8)));
typedef __bf16 bf16x4 __attribute__((ext_vector_type(4)));
typedef float f32x4 __attribute__((ext_vector_type(4)));

__device__ __forceinline__ void load16_lds(const __bf16* g, __bf16* l) {
  __builtin_amdgcn_global_load_lds(
      (const __attribute__((address_space(1))) void*)g,
      (__attribute__((address_space(3))) void*)l, 16, 0, 0);
}

__device__ __forceinline__ float dot8(bf16x8 w, const float* a) {
  float s = 0.f;
#pragma unroll
  for (int j = 0; j < 8; ++j) s += (float)w[j] * a[j];
  return s;
}

// block-wide LN over a 512-elem row held as (v0 @ tid, v1 @ tid+256).
__device__ __forceinline__ void ln_pair(float v0, float v1, int tid,
                                        const float* __restrict__ g,
                                        const float* __restrict__ beta,
                                        float* out, float* ps, float* pq) {
  float s = v0 + v1, sq = v0 * v0 + v1 * v1;
  for (int o = 32; o > 0; o >>= 1) { s += __shfl_xor(s, o); sq += __shfl_xor(sq, o); }
  int wv = tid >> 6;
  if ((tid & 63) == 0) { ps[wv] = s; pq[wv] = sq; }
  __syncthreads();
  s = ps[0] + ps[1] + ps[2] + ps[3];
  sq = pq[0] + pq[1] + pq[2] + pq[3];
  float mean = s * (1.f / DM);
  float rstd = rsqrtf(sq * (1.f / DM) - mean * mean + 1e-5f);
  out[tid] = (v0 - mean) * rstd * g[tid] + beta[tid];
  out[tid + 256] = (v1 - mean) * rstd * g[tid + 256] + beta[tid + 256];
  __syncthreads();
}

// ---------------- PE table ----------------
__global__ __launch_bounds__(256) void pe_kernel(float* __restrict__ pe) {
  int s = blockIdx.x;
  int d2 = threadIdx.x;
  float div = expf((float)(2 * d2) * PE_C);
  float arg = (float)s * div;
  pe[(size_t)s * DM + 2 * d2] = sinf(arg);
  pe[(size_t)s * DM + 2 * d2 + 1] = cosf(arg);
}

// ---------------- embedding (float2 vectorized) ----------------
__global__ __launch_bounds__(256) void embed_enc(const int* __restrict__ x,
                                                 const float* __restrict__ emb,
                                                 const float* __restrict__ pe,
                                                 float* __restrict__ e,
                                                 __bf16* __restrict__ eb) {
  int idx = blockIdx.x * 256 + threadIdx.x;   // 2-elem granule index
  int d2 = idx & 255;
  int bs = idx >> 8;
  int s = bs & (SEQ - 1);
  int tok = x[bs];
  float2 ev = ((const float2*)(emb + (size_t)tok * DM))[d2];
  float2 pv = ((const float2*)(pe + (size_t)s * DM))[d2];
  float v0 = ev.x * EMB_SCALE + pv.x;
  float v1 = ev.y * EMB_SCALE + pv.y;
  ((float2*)e)[idx] = make_float2(v0, v1);
  union { __bf16 h[2]; unsigned u; } pk;
  pk.h[0] = (__bf16)v0; pk.h[1] = (__bf16)v1;
  ((unsigned*)eb)[idx] = pk.u;
}

// ---------------- merged weight transpose fp32[K][N] -> bf16[N][K] ---------
__global__ __launch_bounds__(256) void transpose_w3(
    const float* __restrict__ W0, __bf16* __restrict__ T0, int n0,
    const float* __restrict__ W1, __bf16* __restrict__ T1, int n1,
    const float* __restrict__ W2, __bf16* __restrict__ T2,
    long zmul2, long zadd2, int K, int N) {
  __shared__ float t[32][33];
  int z = blockIdx.z;
  const float* W;
  __bf16* WT;
  if (z < n0) {
    W = W0 + (size_t)z * K * N; WT = T0 + (size_t)z * K * N;
  } else if (z < n0 + n1) {
    int zz = z - n0;
    W = W1 + (size_t)zz * K * N; WT = T1 + (size_t)zz * K * N;
  } else {
    int zz = z - n0 - n1;
    W = W2 + (size_t)(zz * zmul2 + zadd2) * K * N;
    WT = T2 + (size_t)zz * K * N;
  }
  int k0 = blockIdx.y * 32, n0b = blockIdx.x * 32;
  int tx = threadIdx.x & 7, ty = threadIdx.x >> 3;
  float4 v = *(const float4*)&W[(size_t)(k0 + ty) * N + n0b + tx * 4];
  t[ty][tx * 4 + 0] = v.x; t[ty][tx * 4 + 1] = v.y;
  t[ty][tx * 4 + 2] = v.z; t[ty][tx * 4 + 3] = v.w;
  __syncthreads();
  bf16x4 o;
  o[0] = (__bf16)t[tx * 4 + 0][ty];
  o[1] = (__bf16)t[tx * 4 + 1][ty];
  o[2] = (__bf16)t[tx * 4 + 2][ty];
  o[3] = (__bf16)t[tx * 4 + 3][ty];
  *(bf16x4*)&WT[(size_t)(n0b + ty) * K + k0 + tx * 4] = o;
}

// out_w fp32 [512][1000] -> bf16 [1000][512] (guarded tail)
__global__ __launch_bounds__(256) void transpose_ow(const float* __restrict__ W,
                                                    __bf16* __restrict__ WT) {
  __shared__ float t[32][33];
  int n0 = blockIdx.x * 32, k0 = blockIdx.y * 32;
  int tid = threadIdx.x;
  for (int i = tid; i < 1024; i += 256) {
    int kk = i >> 5, nn = i & 31;
    t[kk][nn] = (n0 + nn < OUTD) ? W[(size_t)(k0 + kk) * OUTD + n0 + nn] : 0.f;
  }
  __syncthreads();
  for (int i = tid; i < 1024; i += 256) {
    int nn = i >> 5, kk = i & 31;
    if (n0 + nn < OUTD)
      WT[(size_t)(n0 + nn) * DM + k0 + kk] = (__bf16)t[kk][nn];
  }
}

// ---------------- MFMA GEMM (8 waves, BM=128 x BN=128): R2/R10 structure ---
template <int BN, bool RELU, bool WF32, bool WBF16, bool TRV, bool KVM>
__global__ __launch_bounds__(512) void mfma_gemm8(
    const __bf16* __restrict__ A, const __bf16* __restrict__ BT,
    const float* __restrict__ bias, float* __restrict__ C,
    __bf16* __restrict__ Cb, __bf16* __restrict__ Vt, int M, int N, int K,
    long btStride, long bStride, long cStride) {
  // XCD swizzle: each XCD owns a contiguous y-chunk; x fastest, z slowest.
  int gx = gridDim.x, gy = gridDim.y;
  int lin = blockIdx.x + gx * (blockIdx.y + gy * blockIdx.z);
  int xcd = lin & 7, li = lin >> 3;
  int yc = gy >> 3;
  int bx = li % gx;
  int t2 = li / gx;
  int by = xcd * yc + (t2 % yc);
  int z = t2 / yc;

  if (KVM) {
    long idx = (long)(z >> 1) * 3 + 1 + (z & 1);
    BT += idx * btStride;
    bias += idx * bStride;
  } else {
    BT += (size_t)z * btStride;
    bias += (size_t)z * bStride;
  }
  if (WF32) C += (size_t)z * cStride;
  if (WBF16) Cb += (size_t)z * cStride;

  constexpr int NI = BN / 32;
  __shared__ __bf16 As[2][128 * 64];
  __shared__ __bf16 Bs[2][BN * 64];

  int tid = threadIdx.x;
  int wave = tid >> 6, lane = tid & 63;
  int wm = wave >> 1, wn = wave & 1;           // 4 x 2 wave grid
  int quad = lane >> 4, l16 = lane & 15;
  int rlane = lane >> 3, c8 = lane & 7;
  int m0 = by * 128, n0 = bx * BN;
  int gcol = ((c8 ^ rlane) * 8);

  f32x4 acc[2][NI];
#pragma unroll
  for (int i = 0; i < 2; ++i)
#pragma unroll
    for (int j = 0; j < NI; ++j) acc[i][j] = (f32x4){0.f, 0.f, 0.f, 0.f};

  auto stage = [&](int buf, int k0) {
#pragma unroll
    for (int j = 0; j < 2; ++j) {
      int rb = j * 64 + wave * 8;
      load16_lds(&A[(size_t)(m0 + rb + rlane) * K + k0 + gcol],
                 &As[buf][rb * 64]);
    }
#pragma unroll
    for (int j = 0; j < BN / 64; ++j) {
      int rb = j * 64 + wave * 8;
      load16_lds(&BT[(size_t)(n0 + rb + rlane) * K + k0 + gcol],
                 &Bs[buf][rb * 64]);
    }
  };

  const int NT = K >> 6;
  stage(0, 0);
  __syncthreads();
  for (int t = 0; t < NT; ++t) {
    int cur = t & 1;
    if (t + 1 < NT) stage(cur ^ 1, (t + 1) << 6);
#pragma unroll
    for (int kk = 0; kk < 64; kk += 32) {
      bf16x8 af[2], bfr[NI];
#pragma unroll
      for (int i = 0; i < 2; ++i) {
        int row = wm * 32 + i * 16 + l16;
        af[i] = *(const bf16x8*)&As[cur][row * 64 + ((((kk >> 3) + quad) ^ (row & 7)) * 8)];
      }
#pragma unroll
      for (int i = 0; i < NI; ++i) {
        int row = wn * (BN / 2) + i * 16 + l16;
        bfr[i] = *(const bf16x8*)&Bs[cur][row * 64 + ((((kk >> 3) + quad) ^ (row & 7)) * 8)];
      }
#pragma unroll
      for (int mi = 0; mi < 2; ++mi)
#pragma unroll
        for (int ni = 0; ni < NI; ++ni)
          acc[mi][ni] = __builtin_amdgcn_mfma_f32_16x16x32_bf16(
              af[mi], bfr[ni], acc[mi][ni], 0, 0, 0);
    }
    __syncthreads();
  }

#pragma unroll
  for (int ni = 0; ni < NI; ++ni) {
    int col = n0 + wn * (BN / 2) + ni * 16 + l16;
    float bv = bias[col];
    if (TRV && z == 2) {
      int b = m0 >> 9;
#pragma unroll
      for (int mi = 0; mi < 2; ++mi) {
        int srow = (m0 & 511) + wm * 32 + mi * 16 + quad * 4;
        bf16x4 pk;
#pragma unroll
        for (int r = 0; r < 4; ++r) pk[r] = (__bf16)(acc[mi][ni][r] + bv);
        *(bf16x4*)&Vt[((size_t)(b * 512 + col)) * 512 + srow] = pk;
      }
    } else {
#pragma unroll
      for (int mi = 0; mi < 2; ++mi) {
#pragma unroll
        for (int r = 0; r < 4; ++r) {
          int row = m0 + wm * 32 + mi * 16 + quad * 4 + r;
          float v = acc[mi][ni][r] + bv;
          if (RELU) v = fmaxf(v, 0.f);
          if (WF32) C[(size_t)row * N + col] = v;
          if (WBF16) Cb[(size_t)row * N + col] = (__bf16)v;
        }
      }
    }
  }
}

// ---------------- MFMA GEMM (4 waves, BM=128 x BN=64, split-K): R3 ---------
// Used for FFN2 (N=512, K=2048) where split-K=2 doubles grid fill.
template <int BN, int SK, bool RELU, bool WF32, bool WBF16>
__global__ __launch_bounds__(256) void mfma_gemm(
    const __bf16* __restrict__ A, const __bf16* __restrict__ BT,
    const float* __restrict__ bias, float* __restrict__ C,
    __bf16* __restrict__ Cb, int M, int N, int K, long cStride) {
  int gx = gridDim.x, gy = gridDim.y;
  int lin = blockIdx.x + gx * (blockIdx.y + gy * blockIdx.z);
  int xcd = lin & 7, li = lin >> 3;
  int yc = gy >> 3;
  int bx = li % gx;
  int t2 = li / gx;
  int by = xcd * yc + (t2 % yc);
  int z = t2 / yc;

  if (WF32) C += (size_t)z * cStride;
  if (WBF16) Cb += (size_t)z * cStride;

  constexpr int NI = BN / 32;
  __shared__ __bf16 As[2][128 * 64];
  __shared__ __bf16 Bs[2][BN * 64];

  int tid = threadIdx.x;
  int wave = tid >> 6, lane = tid & 63;
  int wm = wave >> 1, wn = wave & 1;           // 2 x 2 wave grid
  int quad = lane >> 4, l16 = lane & 15;
  int rlane = lane >> 3, c8 = lane & 7;
  int m0 = by * 128, n0 = bx * BN;
  int gcol = ((c8 ^ rlane) * 8);

  f32x4 acc[4][NI];
#pragma unroll
  for (int i = 0; i < 4; ++i)
#pragma unroll
    for (int j = 0; j < NI; ++j) acc[i][j] = (f32x4){0.f, 0.f, 0.f, 0.f};

  auto stage = [&](int buf, int k0) {
#pragma unroll
    for (int j = 0; j < 4; ++j) {
      int rb = j * 32 + wave * 8;
      load16_lds(&A[(size_t)(m0 + rb + rlane) * K + k0 + gcol],
                 &As[buf][rb * 64]);
    }
#pragma unroll
    for (int j = 0; j < BN / 32; ++j) {
      int rb = j * 32 + wave * 8;
      load16_lds(&BT[(size_t)(n0 + rb + rlane) * K + k0 + gcol],
                 &Bs[buf][rb * 64]);
    }
  };

  int kLen = (SK > 1) ? (K / SK) : K;
  int kBeg = (SK > 1) ? z * kLen : 0;
  const int NT = kLen >> 6;
  stage(0, kBeg);
  __syncthreads();
  for (int t = 0; t < NT; ++t) {
    int cur = t & 1;
    if (t + 1 < NT) stage(cur ^ 1, kBeg + ((t + 1) << 6));
#pragma unroll
    for (int kk = 0; kk < 64; kk += 32) {
      bf16x8 af[4], bfr[NI];
#pragma unroll
      for (int i = 0; i < 4; ++i) {
        int row = wm * 64 + i * 16 + l16;
        af[i] = *(const bf16x8*)&As[cur][row * 64 + ((((kk >> 3) + quad) ^ (row & 7)) * 8)];
      }
#pragma unroll
      for (int i = 0; i < NI; ++i) {
        int row = wn * (BN / 2) + i * 16 + l16;
        bfr[i] = *(const bf16x8*)&Bs[cur][row * 64 + ((((kk >> 3) + quad) ^ (row & 7)) * 8)];
      }
#pragma unroll
      for (int mi = 0; mi < 4; ++mi)
#pragma unroll
        for (int ni = 0; ni < NI; ++ni)
          acc[mi][ni] = __builtin_amdgcn_mfma_f32_16x16x32_bf16(
              af[mi], bfr[ni], acc[mi][ni], 0, 0, 0);
    }
    __syncthreads();
  }

#pragma unroll
  for (int ni = 0; ni < NI; ++ni) {
    int col = n0 + wn * (BN / 2) + ni * 16 + l16;
    float bv = (SK == 1 || z == 0) ? bias[col] : 0.f;
#pragma unroll
    for (int mi = 0; mi < 4; ++mi) {
#pragma unroll
      for (int r = 0; r < 4; ++r) {
        int row = m0 + wm * 64 + mi * 16 + quad * 4 + r;
        float v = acc[mi][ni][r] + bv;
        if (RELU) v = fmaxf(v, 0.f);
        if (WF32) C[(size_t)row * N + col] = v;
        if (WBF16) Cb[(size_t)row * N + col] = (__bf16)v;
      }
    }
  }
}

// ---------------- MFMA encoder attention (staged, dbuf prefetch-1) ---------
// R7 structure; output now bf16 (feeds only add_ln; residual dominates sum).
#define SCP 520
__global__ __launch_bounds__(256) void attn_mfma(const __bf16* __restrict__ QKV,
                                                 const __bf16* __restrict__ Vt,
                                                 __bf16* __restrict__ O) {
  __shared__ __bf16 Sc[16 * SCP];
  __shared__ __bf16 Tt[2][64 * 64];

  const long ACTL = (long)NB * SEQ * DM;
  int tid = threadIdx.x;
  int wave = tid >> 6, lane = tid & 63;
  int quad = lane >> 4, l16 = lane & 15;
  int rlane = lane >> 3, c8 = lane & 7;
  // XCD swizzle: chunk by bh so each XCD's L2 holds few K/V panels.
  int lin = blockIdx.x + gridDim.x * blockIdx.y;
  int xcd = lin & 7, li = lin >> 3;
  int yc = gridDim.y >> 3;
  int q0 = (li % gridDim.x) * 16;
  int bh = xcd * yc + li / gridDim.x;
  int b = bh >> 3, h = bh & 7;
  const __bf16* Q = QKV;
  const __bf16* Kp = QKV + ACTL;
  size_t baseQ = ((size_t)b * SEQ + q0) * DM + h * DK;
  size_t baseK = ((size_t)b * SEQ) * DM + h * DK;
  const __bf16* VtB = Vt + ((size_t)(b * 512 + h * 64)) * 512;
  int gcol = (c8 ^ rlane) * 8;

  bf16x8 af0 = *(const bf16x8*)&Q[baseQ + (size_t)l16 * DM + quad * 8];
  bf16x8 af1 = *(const bf16x8*)&Q[baseQ + (size_t)l16 * DM + 32 + quad * 8];

  auto stageK = [&](int buf, int kt) {
#pragma unroll
    for (int j = 0; j < 2; ++j) {
      int row = j * 32 + wave * 8 + rlane;
      load16_lds(&Kp[baseK + (size_t)(kt * 64 + row) * DM + gcol],
                 &Tt[buf][(j * 32 + wave * 8) * 64]);
    }
  };
  auto stageV = [&](int buf, int kt) {
#pragma unroll
    for (int j = 0; j < 2; ++j) {
      int row = j * 32 + wave * 8 + rlane;
      load16_lds(&VtB[(size_t)row * 512 + kt * 64 + gcol],
                 &Tt[buf][(j * 32 + wave * 8) * 64]);
    }
  };

  // ---- QK^T, 8 tiles, prefetch-1 ----
  stageK(0, 0);
  __syncthreads();
  for (int kt = 0; kt < 8; ++kt) {
    int cur = kt & 1;
    if (kt < 7) stageK(cur ^ 1, kt + 1);
    f32x4 acc = (f32x4){0.f, 0.f, 0.f, 0.f};
    int krow = wave * 16 + l16, sw = krow & 7;
    bf16x8 b0 = *(const bf16x8*)&Tt[cur][krow * 64 + ((quad ^ sw) * 8)];
    bf16x8 b1 = *(const bf16x8*)&Tt[cur][krow * 64 + (((4 + quad) ^ sw) * 8)];
    acc = __builtin_amdgcn_mfma_f32_16x16x32_bf16(af0, b0, acc, 0, 0, 0);
    acc = __builtin_amdgcn_mfma_f32_16x16x32_bf16(af1, b1, acc, 0, 0, 0);
#pragma unroll
    for (int r = 0; r < 4; ++r)
      Sc[(quad * 4 + r) * SCP + kt * 64 + wave * 16 + l16] =
          (__bf16)(acc[r] * 0.125f);
    __syncthreads();
  }

  // prefetch first V tile under softmax
  stageV(0, 0);

  // ---- softmax over 16 rows ----
#pragma unroll
  for (int rr = 0; rr < 4; ++rr) {
    int r = wave * 4 + rr;
    float v[8];
    float mx = -1e30f;
#pragma unroll
    for (int j = 0; j < 8; ++j) {
      v[j] = (float)Sc[r * SCP + j * 64 + lane];
      mx = fmaxf(mx, v[j]);
    }
    for (int o = 32; o > 0; o >>= 1) mx = fmaxf(mx, __shfl_xor(mx, o));
    float sum = 0.f;
#pragma unroll
    for (int j = 0; j < 8; ++j) { v[j] = __expf(v[j] - mx); sum += v[j]; }
    for (int o = 32; o > 0; o >>= 1) sum += __shfl_xor(sum, o);
    float inv = 1.f / sum;
#pragma unroll
    for (int j = 0; j < 8; ++j)
      Sc[r * SCP + j * 64 + lane] = (__bf16)(v[j] * inv);
  }
  __syncthreads();  // softmax Sc visible + V tile 0 staged (vmcnt drain)

  // ---- PV, 8 tiles, prefetch-1 ----
  f32x4 oacc = (f32x4){0.f, 0.f, 0.f, 0.f};
  for (int kt = 0; kt < 8; ++kt) {
    int cur = kt & 1;
    if (kt < 7) stageV(cur ^ 1, kt + 1);
    int drow = wave * 16 + l16, sw = drow & 7;
#pragma unroll
    for (int kk = 0; kk < 64; kk += 32) {
      bf16x8 pa = *(const bf16x8*)&Sc[l16 * SCP + kt * 64 + kk + quad * 8];
      bf16x8 vb = *(const bf16x8*)&Tt[cur][drow * 64 + ((((kk >> 3) + quad) ^ sw) * 8)];
      oacc = __builtin_amdgcn_mfma_f32_16x16x32_bf16(pa, vb, oacc, 0, 0, 0);
    }
    __syncthreads();
  }
#pragma unroll
  for (int r = 0; r < 4; ++r)
    O[((size_t)b * SEQ + q0 + quad * 4 + r) * DM + h * DK + wave * 16 + l16] =
        (__bf16)oacc[r];
}

// ---------------- residual + layernorm (float4, 2 rows/block) -------------
// 16B/lane loads (G13 sweet spot). XBF: x operand is bf16 (attn output).
// x2: optional third summand (FFN2 split-K partial). cbias unused -> dropped.
template <bool WB, bool XBF>
__global__ __launch_bounds__(256) void add_ln(
    const float* __restrict__ x, const __bf16* __restrict__ xb,
    const float* __restrict__ x2, const float* __restrict__ res,
    const float* __restrict__ g, const float* __restrict__ beta,
    float* __restrict__ y, __bf16* __restrict__ yb) {
  int tid = threadIdx.x;
  int rloc = tid >> 7;                 // 0/1: which of the block's 2 rows
  int row = blockIdx.x * 2 + rloc;
  int c4 = tid & 127;                  // float4 index within the row
  float4 rv = ((const float4*)(res + (size_t)row * DM))[c4];
  float v0, v1, v2, v3;
  if (XBF) {
    bf16x4 xv = *(const bf16x4*)&xb[(size_t)row * DM + c4 * 4];
    v0 = (float)xv[0] + rv.x; v1 = (float)xv[1] + rv.y;
    v2 = (float)xv[2] + rv.z; v3 = (float)xv[3] + rv.w;
  } else {
    float4 xv = ((const float4*)(x + (size_t)row * DM))[c4];
    v0 = xv.x + rv.x; v1 = xv.y + rv.y; v2 = xv.z + rv.z; v3 = xv.w + rv.w;
  }
  if (x2) {
    float4 q = ((const float4*)(x2 + (size_t)row * DM))[c4];
    v0 += q.x; v1 += q.y; v2 += q.z; v3 += q.w;
  }
  float s = v0 + v1 + v2 + v3;
  float sq = v0 * v0 + v1 * v1 + v2 * v2 + v3 * v3;
  for (int o = 32; o > 0; o >>= 1) {
    s += __shfl_xor(s, o);
    sq += __shfl_xor(sq, o);
  }
  __shared__ float ps[4], pq[4];
  int wv = tid >> 6;                   // waves 2*rloc, 2*rloc+1 hold row rloc
  if ((tid & 63) == 0) { ps[wv] = s; pq[wv] = sq; }
  __syncthreads();
  s = ps[rloc * 2] + ps[rloc * 2 + 1];
  sq = pq[rloc * 2] + pq[rloc * 2 + 1];
  float mean = s * (1.f / DM);
  float rstd = rsqrtf(sq * (1.f / DM) - mean * mean + 1e-5f);
  float4 gg = ((const float4*)g)[c4];
  float4 bb = ((const float4*)beta)[c4];
  float o0 = (v0 - mean) * rstd * gg.x + bb.x;
  float o1 = (v1 - mean) * rstd * gg.y + bb.y;
  float o2 = (v2 - mean) * rstd * gg.z + bb.z;
  float o3 = (v3 - mean) * rstd * gg.w + bb.w;
  ((float4*)(y + (size_t)row * DM))[c4] = make_float4(o0, o1, o2, o3);
  if (WB) {
    bf16x4 pk;
    pk[0] = (__bf16)o0; pk[1] = (__bf16)o1;
    pk[2] = (__bf16)o2; pk[3] = (__bf16)o3;
    *(bf16x4*)&yb[(size_t)row * DM + c4 * 4] = pk;
  }
}

// ============ fused decoder (3 dispatches/layer) ============

// one block per (b,h); LN1/LN3 recomputed redundantly per block (cheap)
template <bool FIRST>
__global__ __launch_bounds__(256) void dec_attn(
    const float* __restrict__ dfp, const float* __restrict__ xp,
    const float* __restrict__ g3, const float* __restrict__ b3,
    const int* __restrict__ target, const float* __restrict__ emb,
    const __bf16* __restrict__ WvT, const float* __restrict__ bv,
    const float* __restrict__ g1, const float* __restrict__ b1ln,
    const __bf16* __restrict__ WqT, const float* __restrict__ qb,
    const __bf16* __restrict__ Kb, const __bf16* __restrict__ Vb,
    float* __restrict__ da, float* __restrict__ tbuf) {
  __shared__ float arow[DM];
  __shared__ float trow[DM];
  __shared__ float red[4][64];
  __shared__ float q[64];
  __shared__ float sc[SEQ];
  __shared__ float wred[4];
  __shared__ float ps[4], pq[4];

  int bh = blockIdx.x, b = bh >> 3, h = bh & 7;
  int tid = threadIdx.x, lane = tid & 63, wave = tid >> 6;

  // ---- dd (layer input) ----
  if (FIRST) {
    int tok = target[b];
    arow[tid] = emb[(size_t)tok * DM + tid] * EMB_SCALE + ((tid & 1) ? 1.f : 0.f);
    arow[tid + 256] =
        emb[(size_t)tok * DM + tid + 256] * EMB_SCALE + ((tid & 1) ? 1.f : 0.f);
    __syncthreads();
  } else {
    float v0 = dfp[(size_t)b * DM + tid] + xp[(size_t)b * DM + tid];
    float v1 = dfp[(size_t)b * DM + tid + 256] + xp[(size_t)b * DM + tid + 256];
    ln_pair(v0, v1, tid, g3, b3, arow, ps, pq);
  }

  // ---- t = LN1(dd + dd@Wv + bv) ----
  float o0, o1;
  {
    const __bf16* w = &WvT[(size_t)tid * DM];
    float acc = 0.f;
#pragma unroll 4
    for (int k = 0; k < DM; k += 8) acc += dot8(*(const bf16x8*)&w[k], &arow[k]);
    o0 = arow[tid] + acc + bv[tid];
  }
  {
    const __bf16* w = &WvT[(size_t)(tid + 256) * DM];
    float acc = 0.f;
#pragma unroll 4
    for (int k = 0; k < DM; k += 8) acc += dot8(*(const bf16x8*)&w[k], &arow[k]);
    o1 = arow[tid + 256] + acc + bv[tid + 256];
  }
  ln_pair(o0, o1, tid, g1, b1ln, trow, ps, pq);
  if (h == 0) {
    tbuf[(size_t)b * DM + tid] = trow[tid];
    tbuf[(size_t)b * DM + tid + 256] = trow[tid + 256];
  }

  // ---- q-gemv: 64 cols x 4 k-subs from trow ----
  {
    int c = tid & 63, s = tid >> 6;
    const __bf16* w = &WqT[(size_t)(h * 64 + c) * DM + s * 128];
    float acc = 0.f;
#pragma unroll
    for (int k = 0; k < 128; k += 8)
      acc += dot8(*(const bf16x8*)&w[k], &trow[s * 128 + k]);
    red[s][c] = acc;
  }
  __syncthreads();
  if (tid < 64)
    q[tid] = red[0][tid] + red[1][tid] + red[2][tid] + red[3][tid] + qb[h * 64 + tid];
  __syncthreads();

  // ---- scores ----
  for (int key = tid; key < SEQ; key += 256) {
    const __bf16* kp = &Kb[((size_t)b * SEQ + key) * DM + h * 64];
    float acc = 0.f;
#pragma unroll
    for (int k = 0; k < 64; k += 8) acc += dot8(*(const bf16x8*)&kp[k], &q[k]);
    sc[key] = acc * 0.125f;
  }
  __syncthreads();
  float m = -1e30f;
  for (int j = tid; j < SEQ; j += 256) m = fmaxf(m, sc[j]);
  for (int o = 32; o > 0; o >>= 1) m = fmaxf(m, __shfl_xor(m, o));
  if (lane == 0) wred[wave] = m;
  __syncthreads();
  m = fmaxf(fmaxf(wred[0], wred[1]), fmaxf(wred[2], wred[3]));
  float sum = 0.f;
  for (int j = tid; j < SEQ; j += 256) {
    float p = __expf(sc[j] - m);
    sc[j] = p;
    sum += p;
  }
  for (int o = 32; o > 0; o >>= 1) sum += __shfl_xor(sum, o);
  __syncthreads();
  if (lane == 0) wred[wave] = sum;
  __syncthreads();
  float inv = 1.f / (wred[0] + wred[1] + wred[2] + wred[3]);

  // ---- PV ----
  {
    int d = tid & 63, s = tid >> 6;
    float acc = 0.f;
    const __bf16* vp = &Vb[((size_t)b * SEQ + s * 128) * DM + h * 64 + d];
#pragma unroll 8
    for (int k = 0; k < 128; ++k) acc += sc[s * 128 + k] * (float)vp[(size_t)k * DM];
    red[s][d] = acc;
  }
  __syncthreads();
  if (tid < 64)
    da[(size_t)b * DM + h * 64 + tid] =
        (red[0][tid] + red[1][tid] + red[2][tid] + red[3][tid]) * inv;
}

// x2 = LN2(da + t) recomputed per block; h = relu(x2@W1+b1); blk0 saves x2
__global__ __launch_bounds__(256) void dec_ffn1f(
    const float* __restrict__ da, const float* __restrict__ tbuf,
    const float* __restrict__ g2, const float* __restrict__ b2ln,
    const __bf16* __restrict__ W1T, const float* __restrict__ b1,
    float* __restrict__ h, float* __restrict__ xbuf) {
  __shared__ float a[8][DM];
  __shared__ float ps[4], pq[4];
  int tid = threadIdx.x, lane = tid & 63, wave = tid >> 6;
  for (int r = 0; r < 8; ++r) {
    float v0 = da[(size_t)r * DM + tid] + tbuf[(size_t)r * DM + tid];
    float v1 = da[(size_t)r * DM + tid + 256] + tbuf[(size_t)r * DM + tid + 256];
    ln_pair(v0, v1, tid, g2, b2ln, a[r], ps, pq);
  }
  int col = blockIdx.x * 4 + wave;
  bf16x8 w = *(const bf16x8*)&W1T[(size_t)col * DM + lane * 8];
  float acc[8];
#pragma unroll
  for (int r = 0; r < 8; ++r) acc[r] = dot8(w, &a[r][lane * 8]);
#pragma unroll
  for (int r = 0; r < 8; ++r)
    for (int o = 32; o > 0; o >>= 1) acc[r] += __shfl_xor(acc[r], o);
  if (lane == 0) {
    float bb = b1[col];
#pragma unroll
    for (int r = 0; r < 8; ++r) h[(size_t)r * DFF + col] = fmaxf(acc[r] + bb, 0.f);
  }
  if (blockIdx.x == 0) {
#pragma unroll
    for (int r = 0; r < 8; ++r) {
      xbuf[(size_t)r * DM + tid] = a[r][tid];
      xbuf[(size_t)r * DM + tid + 256] = a[r][tid + 256];
    }
  }
}

// df[r][col] = h[r] @ W2T[col] + b2[col]; 2 cols/block, 2 waves per col
__global__ __launch_bounds__(256) void dec_ffn2(
    const float* __restrict__ h, const __bf16* __restrict__ W2T,
    const float* __restrict__ b2, float* __restrict__ df) {
  __shared__ float red[4][8];
  int tid = threadIdx.x, lane = tid & 63, wave = tid >> 6;
  int c = wave >> 1, half = wave & 1;
  int col = blockIdx.x * 2 + c;
  int k0 = half * 1024 + lane * 8;
  bf16x8 w0 = *(const bf16x8*)&W2T[(size_t)col * DFF + k0];
  bf16x8 w1 = *(const bf16x8*)&W2T[(size_t)col * DFF + k0 + 512];
  float acc[8];
#pragma unroll
  for (int r = 0; r < 8; ++r) {
    float4 h0a = *(const float4*)&h[(size_t)r * DFF + k0];
    float4 h0b = *(const float4*)&h[(size_t)r * DFF + k0 + 4];
    float4 h1a = *(const float4*)&h[(size_t)r * DFF + k0 + 512];
    float4 h1b = *(const float4*)&h[(size_t)r * DFF + k0 + 516];
    float hh0[8] = {h0a.x, h0a.y, h0a.z, h0a.w, h0b.x, h0b.y, h0b.z, h0b.w};
    float hh1[8] = {h1a.x, h1a.y, h1a.z, h1a.w, h1b.x, h1b.y, h1b.z, h1b.w};
    acc[r] = dot8(w0, hh0) + dot8(w1, hh1);
  }
#pragma unroll
  for (int r = 0; r < 8; ++r)
    for (int o = 32; o > 0; o >>= 1) acc[r] += __shfl_xor(acc[r], o);
  if (lane == 0) {
#pragma unroll
    for (int r = 0; r < 8; ++r) red[wave][r] = acc[r];
  }
  __syncthreads();
  if (tid < 16) {
    int cc = tid >> 3, r = tid & 7;
    int ocol = blockIdx.x * 2 + cc;
    df[(size_t)r * DM + ocol] =
        red[cc * 2][r] + red[cc * 2 + 1][r] + b2[ocol];
  }
}

// out = LN3_5(df + x2) @ Wo + ob  (LN recomputed per block)
__global__ __launch_bounds__(256) void dec_outf(
    const float* __restrict__ df, const float* __restrict__ xbuf,
    const float* __restrict__ g3, const float* __restrict__ b3,
    const __bf16* __restrict__ WoT, const float* __restrict__ ob,
    float* __restrict__ out) {
  __shared__ float a[8][DM];
  __shared__ float ps[4], pq[4];
  int tid = threadIdx.x, lane = tid & 63, wave = tid >> 6;
  for (int r = 0; r < 8; ++r) {
    float v0 = df[(size_t)r * DM + tid] + xbuf[(size_t)r * DM + tid];
    float v1 = df[(size_t)r * DM + tid + 256] + xbuf[(size_t)r * DM + tid + 256];
    ln_pair(v0, v1, tid, g3, b3, a[r], ps, pq);
  }
  int col = blockIdx.x * 4 + wave;
  bf16x8 w = *(const bf16x8*)&WoT[(size_t)col * DM + lane * 8];
  float acc[8];
#pragma unroll
  for (int r = 0; r < 8; ++r) acc[r] = dot8(w, &a[r][lane * 8]);
#pragma unroll
  for (int r = 0; r < 8; ++r)
    for (int o = 32; o > 0; o >>= 1) acc[r] += __shfl_xor(acc[r], o);
  if (lane == 0) {
    float bb = ob[col];
#pragma unroll
    for (int r = 0; r < 8; ++r) out[(size_t)r * OUTD + col] = acc[r] + bb;
  }
}

// ---------------------------------------------------------------------------
extern "C" void kernel_launch(void* const* d_in, const int* in_sizes, int n_in,
                              void* d_out, int out_size, void* d_ws, size_t ws_size,
                              hipStream_t stream) {
  const int* x = (const int*)d_in[0];
  const int* target = (const int*)d_in[1];
  const float* in_emb = (const float*)d_in[2];
  const float* out_emb = (const float*)d_in[3];
  const float* enc_qkv_w = (const float*)d_in[4];
  const float* enc_qkv_b = (const float*)d_in[5];
  const float* enc_ln1_g = (const float*)d_in[6];
  const float* enc_ln1_b = (const float*)d_in[7];
  const float* enc_ffn1_w = (const float*)d_in[8];
  const float* enc_ffn1_b = (const float*)d_in[9];
  const float* enc_ffn2_w = (const float*)d_in[10];
  const float* enc_ffn2_b = (const float*)d_in[11];
  const float* enc_ln2_g = (const float*)d_in[12];
  const float* enc_ln2_b = (const float*)d_in[13];
  const float* dec_qkv1_w = (const float*)d_in[14];
  const float* dec_qkv1_b = (const float*)d_in[15];
  const float* dec_ln1_g = (const float*)d_in[16];
  const float* dec_ln1_b = (const float*)d_in[17];
  const float* dec_qkv2_w = (const float*)d_in[18];
  const float* dec_qkv2_b = (const float*)d_in[19];
  const float* dec_ln2_g = (const float*)d_in[20];
  const float* dec_ln2_b = (const float*)d_in[21];
  const float* dec_ffn1_w = (const float*)d_in[22];
  const float* dec_ffn1_b = (const float*)d_in[23];
  const float* dec_ffn2_w = (const float*)d_in[24];
  const float* dec_ffn2_b = (const float*)d_in[25];
  const float* dec_ln3_g = (const float*)d_in[26];
  const float* dec_ln3_b = (const float*)d_in[27];
  const float* out_w = (const float*)d_in[28];
  const float* out_b = (const float*)d_in[29];

  const long ACTL = (long)NB * SEQ * DM;           // 2M elems
  const int M = NB * SEQ;                           // 4096
  const long WQS = (long)DM * DM;
  const long WFS = (long)DM * DFF;

  char* p = (char*)d_ws;
  float* e = (float*)p;            p += ACTL * 4;
  float* tb = (float*)p;           p += ACTL * 4;
  float* pe = (float*)p;           p += (long)SEQ * DM * 4;
  float* dd = (float*)p;           p += NB * DM * 4;
  float* da = (float*)p;           p += NB * DM * 4;
  float* dh = (float*)p;           p += NB * DFF * 4;
  float* df = (float*)p;           p += NB * DM * 4;
  p = (char*)(((uintptr_t)p + 255) & ~(uintptr_t)255);
  __bf16* eb = (__bf16*)p;         p += ACTL * 2;
  __bf16* qkvb = (__bf16*)p;       p += 3 * ACTL * 2;   // Q,K; slice 2 = V^T
  __bf16* hbb = (__bf16*)p;        p += (long)M * DFF * 2;
  __bf16* kvb = (__bf16*)p;        p += 12L * ACTL * 2; // [layer][K,V][4096][512]
  __bf16* wtq = (__bf16*)p;        p += 18L * WQS * 2;
  __bf16* wtf1 = (__bf16*)p;       p += 6L * WFS * 2;
  __bf16* wtf2 = (__bf16*)p;       p += 6L * WFS * 2;
  __bf16* wtd = (__bf16*)p;        p += 18L * WQS * 2;  // dec_qkv2^T
  __bf16* wtd1 = (__bf16*)p;       p += 18L * WQS * 2;  // dec_qkv1 V-slices^T (6 used)
  __bf16* wf1t = (__bf16*)p;       p += 6L * WFS * 2;
  __bf16* wf2t = (__bf16*)p;       p += 6L * WFS * 2;
  __bf16* wot = (__bf16*)p;        p += (long)OUTD * DM * 2;

  __bf16* vtb = qkvb + 2 * ACTL;
  float* tb2 = (float*)kvb;      // FFN2 split-K partial-1 (kvb idle until KV gemm)
  __bf16* tbb = (__bf16*)tb;     // attn output (bf16 view of tb region)
  float* tbuf = dd;
  float* xbuf = pe;

  // ---- one-time prep (merged transposes: 5 dispatches total) ----
  pe_kernel<<<SEQ, 256, 0, stream>>>(pe);
  transpose_w3<<<dim3(16, 16, 42), 256, 0, stream>>>(
      enc_qkv_w, wtq, 18, dec_qkv2_w, wtd, 18, dec_qkv1_w, wtd1, 3, 2, DM, DM);
  transpose_w3<<<dim3(64, 16, 12), 256, 0, stream>>>(
      enc_ffn1_w, wtf1, 6, dec_ffn1_w, wf1t, 6, nullptr, nullptr, 0, 0, DM, DFF);
  transpose_w3<<<dim3(16, 64, 12), 256, 0, stream>>>(
      enc_ffn2_w, wtf2, 6, dec_ffn2_w, wf2t, 6, nullptr, nullptr, 0, 0, DFF, DM);
  transpose_ow<<<dim3(32, 16), 256, 0, stream>>>(out_w, wot);

  // ---- encoder ----
  embed_enc<<<(M * DM / 2) / 256, 256, 0, stream>>>(x, in_emb, pe, e, eb);
  for (int i = 0; i < NL; ++i) {
    mfma_gemm8<128, false, false, true, true, false><<<dim3(4, 32, 3), 512, 0, stream>>>(
        eb, wtq + (size_t)i * 3 * WQS, enc_qkv_b + (size_t)i * 3 * DM,
        nullptr, qkvb, vtb, M, DM, DM, WQS, DM, ACTL);
    attn_mfma<<<dim3(SEQ / 16, NB * NH), 256, 0, stream>>>(qkvb, vtb, tbb);
    add_ln<true, true><<<M / 2, 256, 0, stream>>>(
        nullptr, tbb, nullptr, e, enc_ln1_g + i * DM, enc_ln1_b + i * DM,
        e, eb);
    mfma_gemm8<128, true, false, true, false, false><<<dim3(16, 32, 1), 512, 0, stream>>>(
        eb, wtf1 + (size_t)i * WFS, enc_ffn1_b + (size_t)i * DFF,
        nullptr, hbb, nullptr, M, DFF, DM, 0, 0, 0);
    mfma_gemm<64, 2, false, true, false><<<dim3(8, 32, 2), 256, 0, stream>>>(
        hbb, wtf2 + (size_t)i * WFS, enc_ffn2_b + (size_t)i * DM,
        tb, nullptr, M, DM, DFF, (long)(tb2 - tb));
    add_ln<true, false><<<M / 2, 256, 0, stream>>>(
        tb, nullptr, tb2, e, enc_ln2_g + i * DM, enc_ln2_b + i * DM,
        e, eb);
  }

  // ---- cross K/V for all 6 layers in one dispatch (bf16 out) ----
  mfma_gemm8<128, false, false, true, false, true><<<dim3(4, 32, 12), 512, 0, stream>>>(
      eb, wtd, dec_qkv2_b, nullptr, kvb, nullptr, M, DM, DM, WQS, DM, ACTL);

  // ---- decoder: 3 dispatches per layer ----
  for (int i = 0; i < NL; ++i) {
    const __bf16* Wv = wtd1 + (size_t)i * WQS;
    const float* bvp = dec_qkv1_b + ((size_t)i * 3 + 2) * DM;
    const __bf16* Wq = wtd + (size_t)i * 3 * WQS;
    const float* qbp = dec_qkv2_b + (size_t)i * 3 * DM;
    const __bf16* Kb = kvb + (size_t)i * 2 * ACTL;
    const __bf16* Vb = kvb + ((size_t)i * 2 + 1) * ACTL;
    if (i == 0)
      dec_attn<true><<<64, 256, 0, stream>>>(
          nullptr, nullptr, nullptr, nullptr, target, out_emb,
          Wv, bvp, dec_ln1_g + i * DM, dec_ln1_b + i * DM,
          Wq, qbp, Kb, Vb, da, tbuf);
    else
      dec_attn<false><<<64, 256, 0, stream>>>(
          df, xbuf, dec_ln3_g + (i - 1) * DM, dec_ln3_b + (i - 1) * DM,
          nullptr, nullptr,
          Wv, bvp, dec_ln1_g + i * DM, dec_ln1_b + i * DM,
          Wq, qbp, Kb, Vb, da, tbuf);
    dec_ffn1f<<<DFF / 4, 256, 0, stream>>>(
        da, tbuf, dec_ln2_g + i * DM, dec_ln2_b + i * DM,
        wf1t + (size_t)i * WFS, dec_ffn1_b + (size_t)i * DFF, dh, xbuf);
    dec_ffn2<<<DM / 2, 256, 0, stream>>>(
        dh, wf2t + (size_t)i * WFS, dec_ffn2_b + (size_t)i * DM, df);
  }

  // ---- output projection (LN3 + gemv + bias fused) ----
  dec_outf<<<OUTD / 4, 256, 0, stream>>>(df, xbuf, dec_ln3_g + 5 * DM,
                                         dec_ln3_b + 5 * DM, wot, out_b,
                                         (float*)d_out);
}